// Round 1
// baseline (543.985 us; speedup 1.0000x reference)
//
#include <hip/hip_runtime.h>
#include <math.h>

#define NN   10000
#define EE   160000
#define ETOT 170000
#define FIN  128
#define C1   1024   // H1*D1
#define NH1  4
#define D1   256
#define D2   256

// ---------------- tiled f32 GEMM: C[M,N] = A[M,K] @ B[K,N] (+bias0+bias1) ----------------
template<int BM, int BN, int BK>
__global__ __launch_bounds__(256)
void gemm_f32(const float* __restrict__ A, const float* __restrict__ B,
              float* __restrict__ C, int M, int N, int K,
              const float* __restrict__ bias0, const float* __restrict__ bias1)
{
    __shared__ float As[BK][BM];
    __shared__ float Bs[BK][BN];
    const int tid = threadIdx.x;
    const int tx = tid & 15, ty = tid >> 4;
    const int m0 = blockIdx.y * BM, n0 = blockIdx.x * BN;
    float acc[4][4] = {};
    for (int k0 = 0; k0 < K; k0 += BK) {
        for (int idx = tid; idx < BM * BK / 4; idx += 256) {
            int m  = idx / (BK / 4);
            int kk = (idx % (BK / 4)) * 4;
            float4 v;
            if (m0 + m < M) v = *(const float4*)&A[(size_t)(m0 + m) * K + k0 + kk];
            else            v = make_float4(0.f, 0.f, 0.f, 0.f);
            As[kk + 0][m] = v.x; As[kk + 1][m] = v.y;
            As[kk + 2][m] = v.z; As[kk + 3][m] = v.w;
        }
        for (int idx = tid; idx < BK * BN / 4; idx += 256) {
            int kk = idx / (BN / 4);
            int n  = (idx % (BN / 4)) * 4;
            *(float4*)&Bs[kk][n] = *(const float4*)&B[(size_t)(k0 + kk) * N + n0 + n];
        }
        __syncthreads();
        #pragma unroll
        for (int k = 0; k < BK; ++k) {
            float4 a = *(const float4*)&As[k][ty << 2];
            float4 b = *(const float4*)&Bs[k][tx << 2];
            float av[4] = {a.x, a.y, a.z, a.w};
            float bv[4] = {b.x, b.y, b.z, b.w};
            #pragma unroll
            for (int i = 0; i < 4; ++i)
                #pragma unroll
                for (int j = 0; j < 4; ++j)
                    acc[i][j] += av[i] * bv[j];
        }
        __syncthreads();
    }
    #pragma unroll
    for (int i = 0; i < 4; ++i) {
        int m = m0 + (ty << 2) + i;
        if (m >= M) continue;
        #pragma unroll
        for (int j = 0; j < 4; ++j) {
            int n = n0 + (tx << 2) + j;
            float v = acc[i][j];
            if (bias0) v += bias0[n];
            if (bias1) v += bias1[n];
            C[(size_t)m * N + n] = v;
        }
    }
}

// ---------------- per-node attention scores, 4 heads (one wave per head) ----------------
__global__ __launch_bounds__(256)
void scores_h4(const float* __restrict__ h, const float* __restrict__ a_src,
               const float* __restrict__ a_dst, float* __restrict__ s_src,
               float* __restrict__ s_dst)
{
    const int n = blockIdx.x;
    const int w = threadIdx.x >> 6;
    const int lane = threadIdx.x & 63;
    float4 v  = ((const float4*)&h[(size_t)n * C1 + w * D1])[lane];
    float4 as = ((const float4*)&a_src[w * D1])[lane];
    float4 ad = ((const float4*)&a_dst[w * D1])[lane];
    float ss = v.x * as.x + v.y * as.y + v.z * as.z + v.w * as.w;
    float sd = v.x * ad.x + v.y * ad.y + v.z * ad.z + v.w * ad.w;
    #pragma unroll
    for (int off = 32; off; off >>= 1) {
        ss += __shfl_xor(ss, off);
        sd += __shfl_xor(sd, off);
    }
    if (lane == 0) { s_src[n * NH1 + w] = ss; s_dst[n * NH1 + w] = sd; }
}

// ---------------- per-node attention scores, 1 head (one wave per node) ----------------
__global__ __launch_bounds__(256)
void scores_h1(const float* __restrict__ h, const float* __restrict__ a_src,
               const float* __restrict__ a_dst, float* __restrict__ s_src,
               float* __restrict__ s_dst)
{
    const int n = blockIdx.x * 4 + (threadIdx.x >> 6);
    if (n >= NN) return;
    const int lane = threadIdx.x & 63;
    float4 v  = ((const float4*)&h[(size_t)n * D2])[lane];
    float4 as = ((const float4*)a_src)[lane];
    float4 ad = ((const float4*)a_dst)[lane];
    float ss = v.x * as.x + v.y * as.y + v.z * as.z + v.w * as.w;
    float sd = v.x * ad.x + v.y * ad.y + v.z * ad.z + v.w * ad.w;
    #pragma unroll
    for (int off = 32; off; off >>= 1) {
        ss += __shfl_xor(ss, off);
        sd += __shfl_xor(sd, off);
    }
    if (lane == 0) { s_src[n] = ss; s_dst[n] = sd; }
}

// ---------------- CSR build ----------------
__global__ void count_deg(const int* __restrict__ dstp, int* __restrict__ cnt)
{
    int e = blockIdx.x * 256 + threadIdx.x;
    if (e >= ETOT) return;
    int d = (e < EE) ? dstp[e] : (e - EE);
    atomicAdd(&cnt[d], 1);
}

__global__ __launch_bounds__(1024)
void scan_kernel(const int* __restrict__ cnt, int* __restrict__ row_ptr)
{
    __shared__ int part[1024];
    const int t = threadIdx.x;
    int local[10];
    int s = 0;
    #pragma unroll
    for (int j = 0; j < 10; ++j) {
        int idx = t * 10 + j;
        local[j] = s;
        s += (idx < NN) ? cnt[idx] : 0;
    }
    part[t] = s;
    __syncthreads();
    for (int off = 1; off < 1024; off <<= 1) {
        int v = (t >= off) ? part[t - off] : 0;
        __syncthreads();
        part[t] += v;
        __syncthreads();
    }
    int prefix = (t > 0) ? part[t - 1] : 0;
    #pragma unroll
    for (int j = 0; j < 10; ++j) {
        int idx = t * 10 + j;
        if (idx < NN) row_ptr[idx] = prefix + local[j];
    }
    if (t == 0) row_ptr[NN] = ETOT;
}

__global__ void scatter_edges(const int* __restrict__ srcp, const int* __restrict__ dstp,
                              const int* __restrict__ row_ptr, int* __restrict__ fill,
                              int* __restrict__ csr_src, int* __restrict__ csr_eid)
{
    int e = blockIdx.x * 256 + threadIdx.x;
    if (e >= ETOT) return;
    int s, d;
    if (e < EE) { s = srcp[e]; d = dstp[e]; } else { s = d = e - EE; }
    int pos = row_ptr[d] + atomicAdd(&fill[d], 1);
    csr_src[pos] = s;
    csr_eid[pos] = e;
}

// ---------------- per-dst segment softmax (1 wave per node) ----------------
template<int H, bool BY_EID>
__global__ __launch_bounds__(64)
void edge_softmax(const float* __restrict__ s_src, const float* __restrict__ s_dst,
                  const int* __restrict__ row_ptr, const int* __restrict__ csr_src,
                  const int* __restrict__ csr_eid, float* __restrict__ alpha)
{
    const int n = blockIdx.x;
    const int lane = threadIdx.x;
    const int start = row_ptr[n], end = row_ptr[n + 1];
    #pragma unroll
    for (int h = 0; h < H; ++h) {
        const float sd = s_dst[n * H + h];
        float m = -1e30f;
        for (int i = start + lane; i < end; i += 64) {
            float sc = s_src[csr_src[i] * H + h] + sd;
            sc = sc > 0.f ? sc : 0.2f * sc;
            m = fmaxf(m, sc);
        }
        #pragma unroll
        for (int off = 32; off; off >>= 1) m = fmaxf(m, __shfl_xor(m, off));
        float z = 0.f;
        for (int i = start + lane; i < end; i += 64) {
            float sc = s_src[csr_src[i] * H + h] + sd;
            sc = sc > 0.f ? sc : 0.2f * sc;
            float p = __expf(sc - m);
            z += p;
            alpha[BY_EID ? (csr_eid[i] * H + h) : i] = p;
        }
        #pragma unroll
        for (int off = 32; off; off >>= 1) z += __shfl_xor(z, off);
        const float inv = 1.f / (z + 1e-16f);
        for (int i = start + lane; i < end; i += 64) {
            alpha[BY_EID ? (csr_eid[i] * H + h) : i] *= inv;
        }
    }
}

// ---------------- layer-1 aggregation + residual + ELU (in place into acc buffer) -------
__global__ __launch_bounds__(256)
void aggregate1(const float* __restrict__ h_pre, const float* __restrict__ alpha,
                const int* __restrict__ row_ptr, const int* __restrict__ csr_src,
                const int* __restrict__ csr_eid, float* __restrict__ h_out)
{
    const int n = blockIdx.x;
    const int t = threadIdx.x;          // thread t covers dims 4t..4t+3; head = t>>6
    const int h = t >> 6;
    const int start = row_ptr[n], end = row_ptr[n + 1];
    float4 acc = make_float4(0.f, 0.f, 0.f, 0.f);
    for (int i = start; i < end; ++i) {
        const int s = csr_src[i];
        const float a = alpha[csr_eid[i] * NH1 + h];
        float4 v = *(const float4*)&h_pre[(size_t)s * C1 + t * 4];
        acc.x += a * v.x; acc.y += a * v.y; acc.z += a * v.z; acc.w += a * v.w;
    }
    float4 base = *(const float4*)&h_out[(size_t)n * C1 + t * 4];
    float4 r;
    r.x = acc.x + base.x; r.y = acc.y + base.y;
    r.z = acc.z + base.z; r.w = acc.w + base.w;
    r.x = r.x > 0.f ? r.x : expm1f(r.x);
    r.y = r.y > 0.f ? r.y : expm1f(r.y);
    r.z = r.z > 0.f ? r.z : expm1f(r.z);
    r.w = r.w > 0.f ? r.w : expm1f(r.w);
    *(float4*)&h_out[(size_t)n * C1 + t * 4] = r;
}

// ---------------- layer-2 aggregation + residual -> final out ----------------
__global__ __launch_bounds__(64)
void aggregate2(const float* __restrict__ h_pre, const float* __restrict__ alpha,
                const int* __restrict__ row_ptr, const int* __restrict__ csr_src,
                const float* __restrict__ accin, float* __restrict__ out)
{
    const int n = blockIdx.x;
    const int t = threadIdx.x;          // 64 threads, thread t covers dims 4t..4t+3
    const int start = row_ptr[n], end = row_ptr[n + 1];
    float4 acc = make_float4(0.f, 0.f, 0.f, 0.f);
    for (int i = start; i < end; ++i) {
        const int s = csr_src[i];
        const float a = alpha[i];
        float4 v = *(const float4*)&h_pre[(size_t)s * D2 + t * 4];
        acc.x += a * v.x; acc.y += a * v.y; acc.z += a * v.z; acc.w += a * v.w;
    }
    float4 base = *(const float4*)&accin[(size_t)n * D2 + t * 4];
    float4 r;
    r.x = acc.x + base.x; r.y = acc.y + base.y;
    r.z = acc.z + base.z; r.w = acc.w + base.w;
    *(float4*)&out[(size_t)n * D2 + t * 4] = r;
}

extern "C" void kernel_launch(void* const* d_in, const int* in_sizes, int n_in,
                              void* d_out, int out_size, void* d_ws, size_t ws_size,
                              hipStream_t stream)
{
    const float* x        = (const float*)d_in[0];
    const int*   ei       = (const int*)  d_in[1];
    const float* W1       = (const float*)d_in[2];
    const float* att_src1 = (const float*)d_in[3];
    const float* att_dst1 = (const float*)d_in[4];
    const float* b1       = (const float*)d_in[5];
    const float* lin1_W   = (const float*)d_in[6];
    const float* lin1_b   = (const float*)d_in[7];
    const float* W2       = (const float*)d_in[8];
    const float* att_src2 = (const float*)d_in[9];
    const float* att_dst2 = (const float*)d_in[10];
    const float* b2       = (const float*)d_in[11];
    const float* lin2_W   = (const float*)d_in[12];
    const float* lin2_b   = (const float*)d_in[13];
    const int* srcp = ei;
    const int* dstp = ei + EE;

    float* out    = (float*)d_out;
    float* alpha1 = out + (size_t)NN * D2;          // [ETOT,4] region of d_out

    float* fw = (float*)d_ws;
    float* h1_pre = fw;   fw += (size_t)NN * C1;    // 10.24M
    float* acc1   = fw;   fw += (size_t)NN * C1;    // lin1 residual -> becomes h1
    float* h2_pre = fw;   fw += (size_t)NN * D2;
    float* acc2   = fw;   fw += (size_t)NN * D2;
    float* s_src1 = fw;   fw += NN * NH1;
    float* s_dst1 = fw;   fw += NN * NH1;
    float* s_src2 = fw;   fw += NN;
    float* s_dst2 = fw;   fw += NN;
    float* alpha2 = fw;   fw += ETOT;
    int* ip      = (int*)fw;
    int* cnt     = ip;    ip += NN;
    int* fill    = ip;    ip += NN;
    int* row_ptr = ip;    ip += NN + 4;
    int* csr_src = ip;    ip += ETOT;
    int* csr_eid = ip;    ip += ETOT;

    hipMemsetAsync(cnt, 0, 2 * NN * sizeof(int), stream);

    const int mtiles = (NN + 63) / 64;
    // layer 1 transforms
    gemm_f32<64,64,32><<<dim3(C1 / 64, mtiles), 256, 0, stream>>>(
        x, W1, h1_pre, NN, C1, FIN, nullptr, nullptr);
    gemm_f32<64,64,32><<<dim3(C1 / 64, mtiles), 256, 0, stream>>>(
        x, lin1_W, acc1, NN, C1, FIN, lin1_b, b1);
    scores_h4<<<NN, 256, 0, stream>>>(h1_pre, att_src1, att_dst1, s_src1, s_dst1);
    // CSR by destination (shared by both layers)
    count_deg<<<(ETOT + 255) / 256, 256, 0, stream>>>(dstp, cnt);
    scan_kernel<<<1, 1024, 0, stream>>>(cnt, row_ptr);
    scatter_edges<<<(ETOT + 255) / 256, 256, 0, stream>>>(srcp, dstp, row_ptr, fill,
                                                          csr_src, csr_eid);
    // layer-1 softmax (alpha1 straight into d_out) + aggregation + ELU
    edge_softmax<NH1, true><<<NN, 64, 0, stream>>>(s_src1, s_dst1, row_ptr,
                                                   csr_src, csr_eid, alpha1);
    aggregate1<<<NN, 256, 0, stream>>>(h1_pre, alpha1, row_ptr, csr_src, csr_eid, acc1);
    // layer 2 transforms (acc1 now holds h1)
    gemm_f32<64,64,32><<<dim3(D2 / 64, mtiles), 256, 0, stream>>>(
        acc1, W2, h2_pre, NN, D2, C1, nullptr, nullptr);
    gemm_f32<64,64,32><<<dim3(D2 / 64, mtiles), 256, 0, stream>>>(
        acc1, lin2_W, acc2, NN, D2, C1, lin2_b, b2);
    scores_h1<<<(NN + 3) / 4, 256, 0, stream>>>(h2_pre, att_src2, att_dst2, s_src2, s_dst2);
    edge_softmax<1, false><<<NN, 64, 0, stream>>>(s_src2, s_dst2, row_ptr,
                                                  csr_src, csr_eid, alpha2);
    aggregate2<<<NN, 64, 0, stream>>>(h2_pre, alpha2, row_ptr, csr_src, acc2, out);
}

// Round 3
// 364.696 us; speedup vs baseline: 1.4916x; 1.4916x over previous
//
#include <hip/hip_runtime.h>
#include <hip/hip_bf16.h>
#include <math.h>

#define NN   10000
#define EE   160000
#define ETOT 170000
#define FIN  128
#define C1   1024   // H1*D1
#define NH1  4
#define D1   256
#define D2   256

typedef __attribute__((ext_vector_type(8))) short bf16x8;
typedef __attribute__((ext_vector_type(4))) float f32x4;

// ---------------- fp32 -> bf16 hi/lo split helpers ----------------
__device__ __forceinline__ void split1(float x, unsigned short &h, unsigned short &l)
{
    __hip_bfloat16 hb = __float2bfloat16(x);
    float r = x - __bfloat162float(hb);
    __hip_bfloat16 lb = __float2bfloat16(r);
    h = __builtin_bit_cast(unsigned short, hb);
    l = __builtin_bit_cast(unsigned short, lb);
}

// Astk[m][0..K-1] = hi, [K..2K-1] = lo
__global__ __launch_bounds__(256)
void split_A(const float* __restrict__ X, unsigned short* __restrict__ A2, int M, int K)
{
    int idx = blockIdx.x * 256 + threadIdx.x;
    int kq4 = K >> 2;
    if (idx >= M * kq4) return;
    int m = idx / kq4, kq = idx % kq4;
    float4 v = *(const float4*)&X[(size_t)m * K + kq * 4];
    ushort4 h, l;
    split1(v.x, h.x, l.x); split1(v.y, h.y, l.y);
    split1(v.z, h.z, l.z); split1(v.w, h.w, l.w);
    unsigned short* row = A2 + (size_t)m * (2 * K);
    *(ushort4*)&row[kq * 4]     = h;
    *(ushort4*)&row[K + kq * 4] = l;
}

// Bt[n][0..K-1] = hi, [K..2K-1] = hi, [2K..3K-1] = lo ; n stacked over {B0, B1}
__global__ __launch_bounds__(256)
void split_Bt(const float* __restrict__ B0, const float* __restrict__ B1,
              int K, int N0, int Ntot, unsigned short* __restrict__ Bt)
{
    int idx = blockIdx.x * 256 + threadIdx.x;
    int total = Ntot * (K >> 2);
    if (idx >= total) return;
    int n = idx % Ntot;
    int kq = idx / Ntot;
    int k = kq * 4;
    const float* B; int nc, nb;
    if (n < N0) { B = B0; nc = n; nb = N0; }
    else        { B = B1; nc = n - N0; nb = Ntot - N0; }
    float v0 = B[(size_t)(k + 0) * nb + nc];
    float v1 = B[(size_t)(k + 1) * nb + nc];
    float v2 = B[(size_t)(k + 2) * nb + nc];
    float v3 = B[(size_t)(k + 3) * nb + nc];
    ushort4 h, l;
    split1(v0, h.x, l.x); split1(v1, h.y, l.y);
    split1(v2, h.z, l.z); split1(v3, h.w, l.w);
    unsigned short* row = Bt + (size_t)n * (3 * K);
    *(ushort4*)&row[k]         = h;
    *(ushort4*)&row[K + k]     = h;
    *(ushort4*)&row[2 * K + k] = l;
}

// ---------------- m97-style bf16 MFMA GEMM ----------------
// A: bf16 [M][lda] row-major, k-index folded: kA = kk % ka2
// Bt: bf16 [Ntot][keff] row-major (B^T, k-contiguous)
// Cfull[m][n] = sum_kk A[m][kk%ka2] * Bt[n][kk]
// n < nsplit -> outP (no bias); n >= nsplit -> outR (+bias0+bias1), ld = ldR
__device__ __forceinline__ void glds16(const void* g, void* l)
{
    __builtin_amdgcn_global_load_lds((const __attribute__((address_space(1))) void*)g,
                                     (__attribute__((address_space(3))) void*)l, 16, 0, 0);
}

__global__ __launch_bounds__(256)
void gemm_split(const unsigned short* __restrict__ A, int lda, int ka2,
                const unsigned short* __restrict__ Bt, int keff,
                float* __restrict__ outP, float* __restrict__ outR,
                int M, int nsplit, int ldR,
                const float* __restrict__ bias0, const float* __restrict__ bias1)
{
    __shared__ __align__(16) unsigned short sA[128 * 32];
    __shared__ __align__(16) unsigned short sB[128 * 32];
    const int tid = threadIdx.x;
    const int w = tid >> 6, lane = tid & 63;
    const int m0 = blockIdx.y * 128;
    const int n0 = blockIdx.x * 128;
    const int wm = w >> 1, wn = w & 1;

    f32x4 acc[4][4] = {};

    // staging: 8 chunks of 16 rows x 32 k (1 KB each); wave w owns chunks 2w, 2w+1
    const int arow0 = (w * 2 + 0) * 16 + (lane >> 2);
    const int arow1 = (w * 2 + 1) * 16 + (lane >> 2);
    int gm0 = m0 + arow0; if (gm0 >= M) gm0 = M - 1;
    int gm1 = m0 + arow1; if (gm1 >= M) gm1 = M - 1;
    const size_t abase0 = (size_t)gm0 * lda + (lane & 3) * 8;
    const size_t abase1 = (size_t)gm1 * lda + (lane & 3) * 8;
    const size_t bbase0 = (size_t)(n0 + arow0) * keff + (lane & 3) * 8;
    const size_t bbase1 = (size_t)(n0 + arow1) * keff + (lane & 3) * 8;
    unsigned short* sA0 = &sA[(w * 2 + 0) * 512];
    unsigned short* sA1 = &sA[(w * 2 + 1) * 512];
    unsigned short* sB0 = &sB[(w * 2 + 0) * 512];
    unsigned short* sB1 = &sB[(w * 2 + 1) * 512];

    const int rA = wm * 64 + (lane & 15);   // + fj*16
    const int rB = wn * 64 + (lane & 15);   // + fi*16
    const int koff = (lane >> 4) * 8;

    for (int kk = 0; kk < keff; kk += 32) {
        const int kA = (kk >= ka2) ? (kk - ka2) : kk;
        glds16(A + abase0 + kA, sA0);
        glds16(A + abase1 + kA, sA1);
        glds16(Bt + bbase0 + kk, sB0);
        glds16(Bt + bbase1 + kk, sB1);
        __syncthreads();
        bf16x8 av[4], bv[4];
        #pragma unroll
        for (int f = 0; f < 4; ++f)
            bv[f] = *(const bf16x8*)&sB[(rB + f * 16) * 32 + koff];
        #pragma unroll
        for (int f = 0; f < 4; ++f)
            av[f] = *(const bf16x8*)&sA[(rA + f * 16) * 32 + koff];
        #pragma unroll
        for (int fj = 0; fj < 4; ++fj)
            #pragma unroll
            for (int fi = 0; fi < 4; ++fi)
                acc[fi][fj] = __builtin_amdgcn_mfma_f32_16x16x32_bf16(
                    bv[fi], av[fj], acc[fi][fj], 0, 0, 0);
        __syncthreads();
    }

    // D of mfma(bv, av): col(lane&15) = C-row (m), row((lane>>4)*4+reg) = C-col (n)
    const int lrow = lane & 15;
    const int lcol = (lane >> 4) << 2;
    #pragma unroll
    for (int fj = 0; fj < 4; ++fj) {
        int row = m0 + wm * 64 + fj * 16 + lrow;
        if (row >= M) continue;
        #pragma unroll
        for (int fi = 0; fi < 4; ++fi) {
            int col = n0 + wn * 64 + fi * 16 + lcol;
            f32x4 v = acc[fi][fj];
            if (col < nsplit) {
                *(f32x4*)&outP[(size_t)row * nsplit + col] = v;
            } else {
                int c = col - nsplit;
                const float4 g0 = *(const float4*)&bias0[c];
                const float4 g1 = *(const float4*)&bias1[c];
                v[0] += g0.x + g1.x; v[1] += g0.y + g1.y;
                v[2] += g0.z + g1.z; v[3] += g0.w + g1.w;
                *(f32x4*)&outR[(size_t)row * ldR + c] = v;
            }
        }
    }
}

// ---------------- per-node attention scores, 4 heads (one wave per head) ----------------
__global__ __launch_bounds__(256)
void scores_h4(const float* __restrict__ h, const float* __restrict__ a_src,
               const float* __restrict__ a_dst, float* __restrict__ s_src,
               float* __restrict__ s_dst)
{
    const int n = blockIdx.x;
    const int w = threadIdx.x >> 6;
    const int lane = threadIdx.x & 63;
    float4 v  = ((const float4*)&h[(size_t)n * C1 + w * D1])[lane];
    float4 as = ((const float4*)&a_src[w * D1])[lane];
    float4 ad = ((const float4*)&a_dst[w * D1])[lane];
    float ss = v.x * as.x + v.y * as.y + v.z * as.z + v.w * as.w;
    float sd = v.x * ad.x + v.y * ad.y + v.z * ad.z + v.w * ad.w;
    #pragma unroll
    for (int off = 32; off; off >>= 1) {
        ss += __shfl_xor(ss, off);
        sd += __shfl_xor(sd, off);
    }
    if (lane == 0) { s_src[n * NH1 + w] = ss; s_dst[n * NH1 + w] = sd; }
}

// ---------------- per-node attention scores, 1 head (one wave per node) ----------------
__global__ __launch_bounds__(256)
void scores_h1(const float* __restrict__ h, const float* __restrict__ a_src,
               const float* __restrict__ a_dst, float* __restrict__ s_src,
               float* __restrict__ s_dst)
{
    const int n = blockIdx.x * 4 + (threadIdx.x >> 6);
    if (n >= NN) return;
    const int lane = threadIdx.x & 63;
    float4 v  = ((const float4*)&h[(size_t)n * D2])[lane];
    float4 as = ((const float4*)a_src)[lane];
    float4 ad = ((const float4*)a_dst)[lane];
    float ss = v.x * as.x + v.y * as.y + v.z * as.z + v.w * as.w;
    float sd = v.x * ad.x + v.y * ad.y + v.z * ad.z + v.w * ad.w;
    #pragma unroll
    for (int off = 32; off; off >>= 1) {
        ss += __shfl_xor(ss, off);
        sd += __shfl_xor(sd, off);
    }
    if (lane == 0) { s_src[n] = ss; s_dst[n] = sd; }
}

// ---------------- CSR build ----------------
__global__ void count_deg(const int* __restrict__ dstp, int* __restrict__ cnt)
{
    int e = blockIdx.x * 256 + threadIdx.x;
    if (e >= ETOT) return;
    int d = (e < EE) ? dstp[e] : (e - EE);
    atomicAdd(&cnt[d], 1);
}

__global__ __launch_bounds__(1024)
void scan_kernel(const int* __restrict__ cnt, int* __restrict__ row_ptr)
{
    __shared__ int part[1024];
    const int t = threadIdx.x;
    int local[10];
    int s = 0;
    #pragma unroll
    for (int j = 0; j < 10; ++j) {
        int idx = t * 10 + j;
        local[j] = s;
        s += (idx < NN) ? cnt[idx] : 0;
    }
    part[t] = s;
    __syncthreads();
    for (int off = 1; off < 1024; off <<= 1) {
        int v = (t >= off) ? part[t - off] : 0;
        __syncthreads();
        part[t] += v;
        __syncthreads();
    }
    int prefix = (t > 0) ? part[t - 1] : 0;
    #pragma unroll
    for (int j = 0; j < 10; ++j) {
        int idx = t * 10 + j;
        if (idx < NN) row_ptr[idx] = prefix + local[j];
    }
    if (t == 0) row_ptr[NN] = ETOT;
}

__global__ void scatter_edges(const int* __restrict__ srcp, const int* __restrict__ dstp,
                              const int* __restrict__ row_ptr, int* __restrict__ fill,
                              int* __restrict__ csr_src, int* __restrict__ csr_eid)
{
    int e = blockIdx.x * 256 + threadIdx.x;
    if (e >= ETOT) return;
    int s, d;
    if (e < EE) { s = srcp[e]; d = dstp[e]; } else { s = d = e - EE; }
    int pos = row_ptr[d] + atomicAdd(&fill[d], 1);
    csr_src[pos] = s;
    csr_eid[pos] = e;
}

// ---------------- per-dst segment softmax (1 wave per node) ----------------
template<int H, bool BY_EID>
__global__ __launch_bounds__(64)
void edge_softmax(const float* __restrict__ s_src, const float* __restrict__ s_dst,
                  const int* __restrict__ row_ptr, const int* __restrict__ csr_src,
                  const int* __restrict__ csr_eid, float* __restrict__ alpha)
{
    const int n = blockIdx.x;
    const int lane = threadIdx.x;
    const int start = row_ptr[n], end = row_ptr[n + 1];
    #pragma unroll
    for (int h = 0; h < H; ++h) {
        const float sd = s_dst[n * H + h];
        float m = -1e30f;
        for (int i = start + lane; i < end; i += 64) {
            float sc = s_src[csr_src[i] * H + h] + sd;
            sc = sc > 0.f ? sc : 0.2f * sc;
            m = fmaxf(m, sc);
        }
        #pragma unroll
        for (int off = 32; off; off >>= 1) m = fmaxf(m, __shfl_xor(m, off));
        float z = 0.f;
        for (int i = start + lane; i < end; i += 64) {
            float sc = s_src[csr_src[i] * H + h] + sd;
            sc = sc > 0.f ? sc : 0.2f * sc;
            float p = __expf(sc - m);
            z += p;
            alpha[BY_EID ? (csr_eid[i] * H + h) : i] = p;
        }
        #pragma unroll
        for (int off = 32; off; off >>= 1) z += __shfl_xor(z, off);
        const float inv = 1.f / (z + 1e-16f);
        for (int i = start + lane; i < end; i += 64) {
            alpha[BY_EID ? (csr_eid[i] * H + h) : i] *= inv;
        }
    }
}

// ---------------- layer-1 aggregation + residual + ELU ----------------
__global__ __launch_bounds__(256)
void aggregate1(const float* __restrict__ h_pre, const float* __restrict__ alpha,
                const int* __restrict__ row_ptr, const int* __restrict__ csr_src,
                const int* __restrict__ csr_eid, float* __restrict__ h_out)
{
    const int n = blockIdx.x;
    const int t = threadIdx.x;
    const int h = t >> 6;
    const int start = row_ptr[n], end = row_ptr[n + 1];
    float4 acc = make_float4(0.f, 0.f, 0.f, 0.f);
    for (int i = start; i < end; ++i) {
        const int s = csr_src[i];
        const float a = alpha[csr_eid[i] * NH1 + h];
        float4 v = *(const float4*)&h_pre[(size_t)s * C1 + t * 4];
        acc.x += a * v.x; acc.y += a * v.y; acc.z += a * v.z; acc.w += a * v.w;
    }
    float4 base = *(const float4*)&h_out[(size_t)n * C1 + t * 4];
    float4 r;
    r.x = acc.x + base.x; r.y = acc.y + base.y;
    r.z = acc.z + base.z; r.w = acc.w + base.w;
    r.x = r.x > 0.f ? r.x : expm1f(r.x);
    r.y = r.y > 0.f ? r.y : expm1f(r.y);
    r.z = r.z > 0.f ? r.z : expm1f(r.z);
    r.w = r.w > 0.f ? r.w : expm1f(r.w);
    *(float4*)&h_out[(size_t)n * C1 + t * 4] = r;
}

// ---------------- layer-2 aggregation + residual -> final out ----------------
__global__ __launch_bounds__(64)
void aggregate2(const float* __restrict__ h_pre, const float* __restrict__ alpha,
                const int* __restrict__ row_ptr, const int* __restrict__ csr_src,
                const float* __restrict__ accin, float* __restrict__ out)
{
    const int n = blockIdx.x;
    const int t = threadIdx.x;
    const int start = row_ptr[n], end = row_ptr[n + 1];
    float4 acc = make_float4(0.f, 0.f, 0.f, 0.f);
    for (int i = start; i < end; ++i) {
        const int s = csr_src[i];
        const float a = alpha[i];
        float4 v = *(const float4*)&h_pre[(size_t)s * D2 + t * 4];
        acc.x += a * v.x; acc.y += a * v.y; acc.z += a * v.z; acc.w += a * v.w;
    }
    float4 base = *(const float4*)&accin[(size_t)n * D2 + t * 4];
    float4 r;
    r.x = acc.x + base.x; r.y = acc.y + base.y;
    r.z = acc.z + base.z; r.w = acc.w + base.w;
    *(float4*)&out[(size_t)n * D2 + t * 4] = r;
}

extern "C" void kernel_launch(void* const* d_in, const int* in_sizes, int n_in,
                              void* d_out, int out_size, void* d_ws, size_t ws_size,
                              hipStream_t stream)
{
    const float* x        = (const float*)d_in[0];
    const int*   ei       = (const int*)  d_in[1];
    const float* W1       = (const float*)d_in[2];
    const float* att_src1 = (const float*)d_in[3];
    const float* att_dst1 = (const float*)d_in[4];
    const float* b1       = (const float*)d_in[5];
    const float* lin1_W   = (const float*)d_in[6];
    const float* lin1_b   = (const float*)d_in[7];
    const float* W2       = (const float*)d_in[8];
    const float* att_src2 = (const float*)d_in[9];
    const float* att_dst2 = (const float*)d_in[10];
    const float* b2       = (const float*)d_in[11];
    const float* lin2_W   = (const float*)d_in[12];
    const float* lin2_b   = (const float*)d_in[13];
    const int* srcp = ei;
    const int* dstp = ei + EE;

    float* out    = (float*)d_out;
    float* alpha1 = out + (size_t)NN * D2;           // [ETOT,4] region of d_out

    float* fw = (float*)d_ws;
    float* h1_pre = fw;   fw += (size_t)NN * C1;     // later reused as A2stk (bf16, same bytes)
    float* acc1   = fw;   fw += (size_t)NN * C1;     // lin1 residual -> h1; later h2_pre|acc2
    unsigned short* A1stk = (unsigned short*)fw; fw += (size_t)NN * FIN;            // [NN][2*FIN] bf16
    unsigned short* Bt1   = (unsigned short*)fw; fw += (size_t)2048 * 3 * FIN / 2;  // [2048][384] bf16
    unsigned short* Bt2   = (unsigned short*)fw; fw += (size_t)512 * 3 * C1 / 2;    // [512][3072] bf16
    float* s_src1 = fw;   fw += NN * NH1;
    float* s_dst1 = fw;   fw += NN * NH1;
    float* s_src2 = fw;   fw += NN;
    float* s_dst2 = fw;   fw += NN;
    float* alpha2 = fw;   fw += ETOT;
    int* ip      = (int*)fw;
    int* cnt     = ip;    ip += NN;
    int* fill    = ip;    ip += NN;
    int* row_ptr = ip;    ip += NN + 4;
    int* csr_src = ip;    ip += ETOT;
    int* csr_eid = ip;    ip += ETOT;

    // aliases (lifetimes do not overlap):
    unsigned short* A2stk = (unsigned short*)h1_pre;  // [NN][2*C1] bf16 == NN*C1 floats
    float* h2_pre = acc1;                             // [NN][D2]
    float* acc2   = acc1 + (size_t)NN * D2;           // [NN][D2]

    hipMemsetAsync(cnt, 0, 2 * NN * sizeof(int), stream);

    const int mt = (NN + 127) / 128;

    // ---- layer 1 transforms (fused W1|lin1_W), split-bf16 MFMA ----
    split_A<<<(NN * (FIN / 4) + 255) / 256, 256, 0, stream>>>(x, A1stk, NN, FIN);
    split_Bt<<<(2048 * (FIN / 4) + 255) / 256, 256, 0, stream>>>(W1, lin1_W, FIN, C1, 2048, Bt1);
    gemm_split<<<dim3(16, mt), 256, 0, stream>>>(A1stk, 2 * FIN, 2 * FIN, Bt1, 3 * FIN,
                                                 h1_pre, acc1, NN, C1, C1, lin1_b, b1);
    scores_h4<<<NN, 256, 0, stream>>>(h1_pre, att_src1, att_dst1, s_src1, s_dst1);

    // ---- CSR by destination (shared by both layers) ----
    count_deg<<<(ETOT + 255) / 256, 256, 0, stream>>>(dstp, cnt);
    scan_kernel<<<1, 1024, 0, stream>>>(cnt, row_ptr);
    scatter_edges<<<(ETOT + 255) / 256, 256, 0, stream>>>(srcp, dstp, row_ptr, fill,
                                                          csr_src, csr_eid);

    // ---- layer-1 softmax + aggregation + ELU ----
    edge_softmax<NH1, true><<<NN, 64, 0, stream>>>(s_src1, s_dst1, row_ptr,
                                                   csr_src, csr_eid, alpha1);
    aggregate1<<<NN, 256, 0, stream>>>(h1_pre, alpha1, row_ptr, csr_src, csr_eid, acc1);

    // ---- layer 2 transforms (fused W2|lin2_W), split-bf16 MFMA ----
    // A2stk overwrites h1_pre (dead); gemm2 outputs overwrite acc1 (h1 dead after split).
    split_A<<<(NN * (C1 / 4) + 255) / 256, 256, 0, stream>>>(acc1, A2stk, NN, C1);
    split_Bt<<<(512 * (C1 / 4) + 255) / 256, 256, 0, stream>>>(W2, lin2_W, C1, D2, 512, Bt2);
    gemm_split<<<dim3(4, mt), 256, 0, stream>>>(A2stk, 2 * C1, 2 * C1, Bt2, 3 * C1,
                                                h2_pre, acc2, NN, D2, D2, lin2_b, b2);

    // ---- layer-2 softmax + aggregation -> out ----
    scores_h1<<<(NN + 3) / 4, 256, 0, stream>>>(h2_pre, att_src2, att_dst2, s_src2, s_dst2);
    edge_softmax<1, false><<<NN, 64, 0, stream>>>(s_src2, s_dst2, row_ptr,
                                                  csr_src, csr_eid, alpha2);
    aggregate2<<<NN, 64, 0, stream>>>(h2_pre, alpha2, row_ptr, csr_src, acc2, out);
}

// Round 4
// 297.684 us; speedup vs baseline: 1.8274x; 1.2251x over previous
//
#include <hip/hip_runtime.h>
#include <hip/hip_bf16.h>
#include <math.h>

#define NN   10000
#define EE   160000
#define ETOT 170000
#define FIN  128
#define C1   1024   // H1*D1
#define NH1  4
#define D1   256
#define D2   256

typedef __attribute__((ext_vector_type(8))) short bf16x8;
typedef __attribute__((ext_vector_type(4))) float f32x4;

// ---------------- bf16 helpers ----------------
__device__ __forceinline__ float b2f(unsigned short u)
{
    union { unsigned int i; float f; } c; c.i = (unsigned int)u << 16; return c.f;
}
__device__ __forceinline__ unsigned short f2b(float x)
{
    return __builtin_bit_cast(unsigned short, __float2bfloat16(x));
}
__device__ __forceinline__ void split1(float x, unsigned short &h, unsigned short &l)
{
    __hip_bfloat16 hb = __float2bfloat16(x);
    float r = x - __bfloat162float(hb);
    h = __builtin_bit_cast(unsigned short, hb);
    l = __builtin_bit_cast(unsigned short, __float2bfloat16(r));
}

// Astk[m][0..K-1] = hi, [K..2K-1] = lo
__global__ __launch_bounds__(256)
void split_A(const float* __restrict__ X, unsigned short* __restrict__ A2, int M, int K)
{
    int idx = blockIdx.x * 256 + threadIdx.x;
    int kq4 = K >> 2;
    if (idx >= M * kq4) return;
    int m = idx / kq4, kq = idx % kq4;
    float4 v = *(const float4*)&X[(size_t)m * K + kq * 4];
    ushort4 h, l;
    split1(v.x, h.x, l.x); split1(v.y, h.y, l.y);
    split1(v.z, h.z, l.z); split1(v.w, h.w, l.w);
    unsigned short* row = A2 + (size_t)m * (2 * K);
    *(ushort4*)&row[kq * 4]     = h;
    *(ushort4*)&row[K + kq * 4] = l;
}

// Bt[n][0..K-1] = hi, [K..2K-1] = hi, [2K..3K-1] = lo ; n stacked over {B0, B1}
__global__ __launch_bounds__(256)
void split_Bt(const float* __restrict__ B0, const float* __restrict__ B1,
              int K, int N0, int Ntot, unsigned short* __restrict__ Bt)
{
    int idx = blockIdx.x * 256 + threadIdx.x;
    int total = Ntot * (K >> 2);
    if (idx >= total) return;
    int n = idx % Ntot;
    int kq = idx / Ntot;
    int k = kq * 4;
    const float* B; int nc, nb;
    if (n < N0) { B = B0; nc = n; nb = N0; }
    else        { B = B1; nc = n - N0; nb = Ntot - N0; }
    float v0 = B[(size_t)(k + 0) * nb + nc];
    float v1 = B[(size_t)(k + 1) * nb + nc];
    float v2 = B[(size_t)(k + 2) * nb + nc];
    float v3 = B[(size_t)(k + 3) * nb + nc];
    ushort4 h, l;
    split1(v0, h.x, l.x); split1(v1, h.y, l.y);
    split1(v2, h.z, l.z); split1(v3, h.w, l.w);
    unsigned short* row = Bt + (size_t)n * (3 * K);
    *(ushort4*)&row[k]         = h;
    *(ushort4*)&row[K + k]     = h;
    *(ushort4*)&row[2 * K + k] = l;
}

// ---------------- split-bf16 MFMA GEMM ----------------
// Cfull[m][n] = sum_kk A[m][kk%ka2] * Bt[n][kk]
// n < nsplit -> outPb (bf16, no bias); n >= nsplit -> outR (f32, +bias0+bias1)
__device__ __forceinline__ void glds16(const void* g, void* l)
{
    __builtin_amdgcn_global_load_lds((const __attribute__((address_space(1))) void*)g,
                                     (__attribute__((address_space(3))) void*)l, 16, 0, 0);
}

__global__ __launch_bounds__(256)
void gemm_split(const unsigned short* __restrict__ A, int lda, int ka2,
                const unsigned short* __restrict__ Bt, int keff,
                unsigned short* __restrict__ outPb, float* __restrict__ outR,
                int M, int nsplit, int ldR,
                const float* __restrict__ bias0, const float* __restrict__ bias1)
{
    __shared__ __align__(16) unsigned short sA[128 * 32];
    __shared__ __align__(16) unsigned short sB[128 * 32];
    const int tid = threadIdx.x;
    const int w = tid >> 6, lane = tid & 63;
    const int m0 = blockIdx.y * 128;
    const int n0 = blockIdx.x * 128;
    const int wm = w >> 1, wn = w & 1;

    f32x4 acc[4][4] = {};

    const int arow0 = (w * 2 + 0) * 16 + (lane >> 2);
    const int arow1 = (w * 2 + 1) * 16 + (lane >> 2);
    int gm0 = m0 + arow0; if (gm0 >= M) gm0 = M - 1;
    int gm1 = m0 + arow1; if (gm1 >= M) gm1 = M - 1;
    const size_t abase0 = (size_t)gm0 * lda + (lane & 3) * 8;
    const size_t abase1 = (size_t)gm1 * lda + (lane & 3) * 8;
    const size_t bbase0 = (size_t)(n0 + arow0) * keff + (lane & 3) * 8;
    const size_t bbase1 = (size_t)(n0 + arow1) * keff + (lane & 3) * 8;
    unsigned short* sA0 = &sA[(w * 2 + 0) * 512];
    unsigned short* sA1 = &sA[(w * 2 + 1) * 512];
    unsigned short* sB0 = &sB[(w * 2 + 0) * 512];
    unsigned short* sB1 = &sB[(w * 2 + 1) * 512];

    const int rA = wm * 64 + (lane & 15);
    const int rB = wn * 64 + (lane & 15);
    const int koff = (lane >> 4) * 8;

    for (int kk = 0; kk < keff; kk += 32) {
        const int kA = (kk >= ka2) ? (kk - ka2) : kk;
        glds16(A + abase0 + kA, sA0);
        glds16(A + abase1 + kA, sA1);
        glds16(Bt + bbase0 + kk, sB0);
        glds16(Bt + bbase1 + kk, sB1);
        __syncthreads();
        bf16x8 av[4], bv[4];
        #pragma unroll
        for (int f = 0; f < 4; ++f)
            bv[f] = *(const bf16x8*)&sB[(rB + f * 16) * 32 + koff];
        #pragma unroll
        for (int f = 0; f < 4; ++f)
            av[f] = *(const bf16x8*)&sA[(rA + f * 16) * 32 + koff];
        #pragma unroll
        for (int fj = 0; fj < 4; ++fj)
            #pragma unroll
            for (int fi = 0; fi < 4; ++fi)
                acc[fi][fj] = __builtin_amdgcn_mfma_f32_16x16x32_bf16(
                    bv[fi], av[fj], acc[fi][fj], 0, 0, 0);
        __syncthreads();
    }

    const int lrow = lane & 15;
    const int lcol = (lane >> 4) << 2;
    #pragma unroll
    for (int fj = 0; fj < 4; ++fj) {
        int row = m0 + wm * 64 + fj * 16 + lrow;
        if (row >= M) continue;
        #pragma unroll
        for (int fi = 0; fi < 4; ++fi) {
            int col = n0 + wn * 64 + fi * 16 + lcol;
            f32x4 v = acc[fi][fj];
            if (col < nsplit) {
                ushort4 o;
                o.x = f2b(v[0]); o.y = f2b(v[1]); o.z = f2b(v[2]); o.w = f2b(v[3]);
                *(ushort4*)&outPb[(size_t)row * nsplit + col] = o;
            } else {
                int c = col - nsplit;
                const float4 g0 = *(const float4*)&bias0[c];
                const float4 g1 = *(const float4*)&bias1[c];
                v[0] += g0.x + g1.x; v[1] += g0.y + g1.y;
                v[2] += g0.z + g1.z; v[3] += g0.w + g1.w;
                *(f32x4*)&outR[(size_t)row * ldR + c] = v;
            }
        }
    }
}

// ---------------- per-node attention scores (bf16 h), 4 heads ----------------
__global__ __launch_bounds__(256)
void scores_h4(const unsigned short* __restrict__ h, const float* __restrict__ a_src,
               const float* __restrict__ a_dst, float* __restrict__ s_src,
               float* __restrict__ s_dst)
{
    const int n = blockIdx.x;
    const int w = threadIdx.x >> 6;
    const int lane = threadIdx.x & 63;
    ushort4 u = *(const ushort4*)&h[(size_t)n * C1 + w * D1 + lane * 4];
    float4 as = ((const float4*)&a_src[w * D1])[lane];
    float4 ad = ((const float4*)&a_dst[w * D1])[lane];
    float vx = b2f(u.x), vy = b2f(u.y), vz = b2f(u.z), vw = b2f(u.w);
    float ss = vx * as.x + vy * as.y + vz * as.z + vw * as.w;
    float sd = vx * ad.x + vy * ad.y + vz * ad.z + vw * ad.w;
    #pragma unroll
    for (int off = 32; off; off >>= 1) {
        ss += __shfl_xor(ss, off);
        sd += __shfl_xor(sd, off);
    }
    if (lane == 0) { s_src[n * NH1 + w] = ss; s_dst[n * NH1 + w] = sd; }
}

// ---------------- per-node attention scores (bf16 h), 1 head ----------------
__global__ __launch_bounds__(256)
void scores_h1(const unsigned short* __restrict__ h, const float* __restrict__ a_src,
               const float* __restrict__ a_dst, float* __restrict__ s_src,
               float* __restrict__ s_dst)
{
    const int n = blockIdx.x * 4 + (threadIdx.x >> 6);
    if (n >= NN) return;
    const int lane = threadIdx.x & 63;
    ushort4 u = *(const ushort4*)&h[(size_t)n * D2 + lane * 4];
    float4 as = ((const float4*)a_src)[lane];
    float4 ad = ((const float4*)a_dst)[lane];
    float vx = b2f(u.x), vy = b2f(u.y), vz = b2f(u.z), vw = b2f(u.w);
    float ss = vx * as.x + vy * as.y + vz * as.z + vw * as.w;
    float sd = vx * ad.x + vy * ad.y + vz * ad.z + vw * ad.w;
    #pragma unroll
    for (int off = 32; off; off >>= 1) {
        ss += __shfl_xor(ss, off);
        sd += __shfl_xor(sd, off);
    }
    if (lane == 0) { s_src[n] = ss; s_dst[n] = sd; }
}

// ---------------- CSR build ----------------
__global__ void count_deg(const int* __restrict__ dstp, int* __restrict__ cnt)
{
    int e = blockIdx.x * 256 + threadIdx.x;
    if (e >= ETOT) return;
    int d = (e < EE) ? dstp[e] : (e - EE);
    atomicAdd(&cnt[d], 1);
}

__global__ __launch_bounds__(1024)
void scan_kernel(const int* __restrict__ cnt, int* __restrict__ row_ptr)
{
    __shared__ int part[1024];
    const int t = threadIdx.x;
    int local[10];
    int s = 0;
    #pragma unroll
    for (int j = 0; j < 10; ++j) {
        int idx = t * 10 + j;
        local[j] = s;
        s += (idx < NN) ? cnt[idx] : 0;
    }
    part[t] = s;
    __syncthreads();
    for (int off = 1; off < 1024; off <<= 1) {
        int v = (t >= off) ? part[t - off] : 0;
        __syncthreads();
        part[t] += v;
        __syncthreads();
    }
    int prefix = (t > 0) ? part[t - 1] : 0;
    #pragma unroll
    for (int j = 0; j < 10; ++j) {
        int idx = t * 10 + j;
        if (idx < NN) row_ptr[idx] = prefix + local[j];
    }
    if (t == 0) row_ptr[NN] = ETOT;
}

__global__ void scatter_edges(const int* __restrict__ srcp, const int* __restrict__ dstp,
                              const int* __restrict__ row_ptr, int* __restrict__ fill,
                              int* __restrict__ csr_src, int* __restrict__ csr_eid)
{
    int e = blockIdx.x * 256 + threadIdx.x;
    if (e >= ETOT) return;
    int s, d;
    if (e < EE) { s = srcp[e]; d = dstp[e]; } else { s = d = e - EE; }
    int pos = row_ptr[d] + atomicAdd(&fill[d], 1);
    csr_src[pos] = s;
    csr_eid[pos] = e;
}

// ---------------- per-dst segment softmax (1 wave per node) ----------------
template<int H, bool BY_EID>
__global__ __launch_bounds__(64)
void edge_softmax(const float* __restrict__ s_src, const float* __restrict__ s_dst,
                  const int* __restrict__ row_ptr, const int* __restrict__ csr_src,
                  const int* __restrict__ csr_eid, float* __restrict__ alpha)
{
    const int n = blockIdx.x;
    const int lane = threadIdx.x;
    const int start = row_ptr[n], end = row_ptr[n + 1];
    #pragma unroll
    for (int h = 0; h < H; ++h) {
        const float sd = s_dst[n * H + h];
        float m = -1e30f;
        for (int i = start + lane; i < end; i += 64) {
            float sc = s_src[csr_src[i] * H + h] + sd;
            sc = sc > 0.f ? sc : 0.2f * sc;
            m = fmaxf(m, sc);
        }
        #pragma unroll
        for (int off = 32; off; off >>= 1) m = fmaxf(m, __shfl_xor(m, off));
        float z = 0.f;
        for (int i = start + lane; i < end; i += 64) {
            float sc = s_src[csr_src[i] * H + h] + sd;
            sc = sc > 0.f ? sc : 0.2f * sc;
            float p = __expf(sc - m);
            z += p;
            alpha[BY_EID ? (csr_eid[i] * H + h) : i] = p;
        }
        #pragma unroll
        for (int off = 32; off; off >>= 1) z += __shfl_xor(z, off);
        const float inv = 1.f / (z + 1e-16f);
        for (int i = start + lane; i < end; i += 64) {
            alpha[BY_EID ? (csr_eid[i] * H + h) : i] *= inv;
        }
    }
}

// -------- layer-1 aggregation + residual + ELU -> writes hi|lo bf16 split (A2stk) ------
// a2stk aliases base_in (same bytes); base read + barrier precede all writes.
__global__ __launch_bounds__(256)
void aggregate1(const unsigned short* __restrict__ h1b, const float* __restrict__ alpha,
                const int* __restrict__ row_ptr, const int* __restrict__ csr_src,
                const int* __restrict__ csr_eid, const float* __restrict__ base_in,
                unsigned short* __restrict__ a2stk)
{
    const int n = blockIdx.x;
    const int t = threadIdx.x;          // dims 4t..4t+3; head = t>>6
    const int h = t >> 6;
    const int start = row_ptr[n], end = row_ptr[n + 1];
    float4 base = *(const float4*)&base_in[(size_t)n * C1 + t * 4];
    float4 acc = make_float4(0.f, 0.f, 0.f, 0.f);
    ushort4 v_nxt = make_ushort4(0, 0, 0, 0);
    float a_nxt = 0.f;
    {
        int s = csr_src[start];
        a_nxt = alpha[(size_t)csr_eid[start] * NH1 + h];
        v_nxt = *(const ushort4*)&h1b[(size_t)s * C1 + t * 4];
    }
    for (int i = start; i < end; ++i) {
        ushort4 v = v_nxt; float a = a_nxt;
        if (i + 1 < end) {
            int s2 = csr_src[i + 1];
            a_nxt = alpha[(size_t)csr_eid[i + 1] * NH1 + h];
            v_nxt = *(const ushort4*)&h1b[(size_t)s2 * C1 + t * 4];
        }
        acc.x += a * b2f(v.x); acc.y += a * b2f(v.y);
        acc.z += a * b2f(v.z); acc.w += a * b2f(v.w);
    }
    float4 r;
    r.x = acc.x + base.x; r.y = acc.y + base.y;
    r.z = acc.z + base.z; r.w = acc.w + base.w;
    r.x = r.x > 0.f ? r.x : expm1f(r.x);
    r.y = r.y > 0.f ? r.y : expm1f(r.y);
    r.z = r.z > 0.f ? r.z : expm1f(r.z);
    r.w = r.w > 0.f ? r.w : expm1f(r.w);
    __syncthreads();    // all base_in reads done before in-place overwrite
    ushort4 hi, lo;
    split1(r.x, hi.x, lo.x); split1(r.y, hi.y, lo.y);
    split1(r.z, hi.z, lo.z); split1(r.w, hi.w, lo.w);
    unsigned short* row = a2stk + (size_t)n * (2 * C1);
    *(ushort4*)&row[t * 4]      = hi;
    *(ushort4*)&row[C1 + t * 4] = lo;
}

// ---------------- layer-2 aggregation + residual -> final out ----------------
__global__ __launch_bounds__(64)
void aggregate2(const unsigned short* __restrict__ h2b, const float* __restrict__ alpha,
                const int* __restrict__ row_ptr, const int* __restrict__ csr_src,
                const float* __restrict__ accin, float* __restrict__ out)
{
    const int n = blockIdx.x;
    const int t = threadIdx.x;          // dims 4t..4t+3
    const int start = row_ptr[n], end = row_ptr[n + 1];
    float4 acc = make_float4(0.f, 0.f, 0.f, 0.f);
    ushort4 v_nxt = make_ushort4(0, 0, 0, 0);
    float a_nxt = 0.f;
    {
        int s = csr_src[start];
        a_nxt = alpha[start];
        v_nxt = *(const ushort4*)&h2b[(size_t)s * D2 + t * 4];
    }
    for (int i = start; i < end; ++i) {
        ushort4 v = v_nxt; float a = a_nxt;
        if (i + 1 < end) {
            int s2 = csr_src[i + 1];
            a_nxt = alpha[i + 1];
            v_nxt = *(const ushort4*)&h2b[(size_t)s2 * D2 + t * 4];
        }
        acc.x += a * b2f(v.x); acc.y += a * b2f(v.y);
        acc.z += a * b2f(v.z); acc.w += a * b2f(v.w);
    }
    float4 base = *(const float4*)&accin[(size_t)n * D2 + t * 4];
    float4 r;
    r.x = acc.x + base.x; r.y = acc.y + base.y;
    r.z = acc.z + base.z; r.w = acc.w + base.w;
    *(float4*)&out[(size_t)n * D2 + t * 4] = r;
}

extern "C" void kernel_launch(void* const* d_in, const int* in_sizes, int n_in,
                              void* d_out, int out_size, void* d_ws, size_t ws_size,
                              hipStream_t stream)
{
    const float* x        = (const float*)d_in[0];
    const int*   ei       = (const int*)  d_in[1];
    const float* W1       = (const float*)d_in[2];
    const float* att_src1 = (const float*)d_in[3];
    const float* att_dst1 = (const float*)d_in[4];
    const float* b1       = (const float*)d_in[5];
    const float* lin1_W   = (const float*)d_in[6];
    const float* lin1_b   = (const float*)d_in[7];
    const float* W2       = (const float*)d_in[8];
    const float* att_src2 = (const float*)d_in[9];
    const float* att_dst2 = (const float*)d_in[10];
    const float* b2       = (const float*)d_in[11];
    const float* lin2_W   = (const float*)d_in[12];
    const float* lin2_b   = (const float*)d_in[13];
    const int* srcp = ei;
    const int* dstp = ei + EE;

    float* out    = (float*)d_out;
    float* alpha1 = out + (size_t)NN * D2;           // [ETOT,4] region of d_out

    float* fw = (float*)d_ws;
    float* acc1   = fw;   fw += (size_t)NN * C1;     // lin1 residual; becomes A2stk (bf16 hi|lo)
    unsigned short* h1b = (unsigned short*)fw; fw += (size_t)NN * C1 / 2;   // [NN][C1] bf16
    unsigned short* h2b = (unsigned short*)fw; fw += (size_t)NN * D2 / 2;   // [NN][D2] bf16
    float* acc2   = fw;   fw += (size_t)NN * D2;     // lin2 residual
    unsigned short* A1stk = (unsigned short*)fw; fw += (size_t)NN * FIN;            // [NN][2*FIN] bf16
    unsigned short* Bt1   = (unsigned short*)fw; fw += (size_t)2048 * 3 * FIN / 2;  // [2048][384]
    unsigned short* Bt2   = (unsigned short*)fw; fw += (size_t)512 * 3 * C1 / 2;    // [512][3072]
    float* s_src1 = fw;   fw += NN * NH1;
    float* s_dst1 = fw;   fw += NN * NH1;
    float* s_src2 = fw;   fw += NN;
    float* s_dst2 = fw;   fw += NN;
    float* alpha2 = fw;   fw += ETOT;
    int* ip      = (int*)fw;
    int* cnt     = ip;    ip += NN;
    int* fill    = ip;    ip += NN;
    int* row_ptr = ip;    ip += NN + 4;
    int* csr_src = ip;    ip += ETOT;
    int* csr_eid = ip;    ip += ETOT;

    unsigned short* A2stk = (unsigned short*)acc1;   // alias: [NN][2*C1] bf16, in-place

    hipMemsetAsync(cnt, 0, 2 * NN * sizeof(int), stream);

    const int mt = (NN + 127) / 128;

    // ---- layer 1 transforms (fused W1|lin1_W), split-bf16 MFMA ----
    split_A<<<(NN * (FIN / 4) + 255) / 256, 256, 0, stream>>>(x, A1stk, NN, FIN);
    split_Bt<<<(2048 * (FIN / 4) + 255) / 256, 256, 0, stream>>>(W1, lin1_W, FIN, C1, 2048, Bt1);
    gemm_split<<<dim3(16, mt), 256, 0, stream>>>(A1stk, 2 * FIN, 2 * FIN, Bt1, 3 * FIN,
                                                 h1b, acc1, NN, C1, C1, lin1_b, b1);
    scores_h4<<<NN, 256, 0, stream>>>(h1b, att_src1, att_dst1, s_src1, s_dst1);

    // ---- CSR by destination (shared by both layers) ----
    count_deg<<<(ETOT + 255) / 256, 256, 0, stream>>>(dstp, cnt);
    scan_kernel<<<1, 1024, 0, stream>>>(cnt, row_ptr);
    scatter_edges<<<(ETOT + 255) / 256, 256, 0, stream>>>(srcp, dstp, row_ptr, fill,
                                                          csr_src, csr_eid);

    // ---- layer-1 softmax + aggregation + ELU (+fused hi/lo split, in place) ----
    edge_softmax<NH1, true><<<NN, 64, 0, stream>>>(s_src1, s_dst1, row_ptr,
                                                   csr_src, csr_eid, alpha1);
    aggregate1<<<NN, 256, 0, stream>>>(h1b, alpha1, row_ptr, csr_src, csr_eid,
                                       acc1, A2stk);

    // ---- layer 2 transforms (fused W2|lin2_W), split-bf16 MFMA ----
    split_Bt<<<(512 * (C1 / 4) + 255) / 256, 256, 0, stream>>>(W2, lin2_W, C1, D2, 512, Bt2);
    gemm_split<<<dim3(4, mt), 256, 0, stream>>>(A2stk, 2 * C1, 2 * C1, Bt2, 3 * C1,
                                                h2b, acc2, NN, D2, D2, lin2_b, b2);

    // ---- layer-2 softmax + aggregation -> out ----
    scores_h1<<<(NN + 3) / 4, 256, 0, stream>>>(h2b, att_src2, att_dst2, s_src2, s_dst2);
    edge_softmax<1, false><<<NN, 64, 0, stream>>>(s_src2, s_dst2, row_ptr,
                                                  csr_src, csr_eid, alpha2);
    aggregate2<<<NN, 64, 0, stream>>>(h2b, alpha2, row_ptr, csr_src, acc2, out);
}

// Round 5
// 268.767 us; speedup vs baseline: 2.0240x; 1.1076x over previous
//
#include <hip/hip_runtime.h>
#include <hip/hip_bf16.h>
#include <math.h>

#define NN   10000
#define EE   160000
#define ETOT 170000
#define FIN  128
#define C1   1024   // H1*D1
#define NH1  4
#define D1   256
#define D2   256

typedef __attribute__((ext_vector_type(8))) short bf16x8;
typedef __attribute__((ext_vector_type(4))) float f32x4;

// ---------------- bf16 helpers ----------------
__device__ __forceinline__ float b2f(unsigned short u)
{
    union { unsigned int i; float f; } c; c.i = (unsigned int)u << 16; return c.f;
}
__device__ __forceinline__ unsigned short f2b(float x)
{
    return __builtin_bit_cast(unsigned short, __float2bfloat16(x));
}
__device__ __forceinline__ void split1(float x, unsigned short &h, unsigned short &l)
{
    __hip_bfloat16 hb = __float2bfloat16(x);
    float r = x - __bfloat162float(hb);
    h = __builtin_bit_cast(unsigned short, hb);
    l = __builtin_bit_cast(unsigned short, __float2bfloat16(r));
}

// Astk[m][0..K-1] = hi, [K..2K-1] = lo
__global__ __launch_bounds__(256)
void split_A(const float* __restrict__ X, unsigned short* __restrict__ A2, int M, int K)
{
    int idx = blockIdx.x * 256 + threadIdx.x;
    int kq4 = K >> 2;
    if (idx >= M * kq4) return;
    int m = idx / kq4, kq = idx % kq4;
    float4 v = *(const float4*)&X[(size_t)m * K + kq * 4];
    ushort4 h, l;
    split1(v.x, h.x, l.x); split1(v.y, h.y, l.y);
    split1(v.z, h.z, l.z); split1(v.w, h.w, l.w);
    unsigned short* row = A2 + (size_t)m * (2 * K);
    *(ushort4*)&row[kq * 4]     = h;
    *(ushort4*)&row[K + kq * 4] = l;
}

// Bt[n][0..K-1] = hi, [K..2K-1] = hi, [2K..3K-1] = lo ; n stacked over {B0, B1}
__global__ __launch_bounds__(256)
void split_Bt(const float* __restrict__ B0, const float* __restrict__ B1,
              int K, int N0, int Ntot, unsigned short* __restrict__ Bt)
{
    int idx = blockIdx.x * 256 + threadIdx.x;
    int total = Ntot * (K >> 2);
    if (idx >= total) return;
    int n = idx % Ntot;
    int kq = idx / Ntot;
    int k = kq * 4;
    const float* B; int nc, nb;
    if (n < N0) { B = B0; nc = n; nb = N0; }
    else        { B = B1; nc = n - N0; nb = Ntot - N0; }
    float v0 = B[(size_t)(k + 0) * nb + nc];
    float v1 = B[(size_t)(k + 1) * nb + nc];
    float v2 = B[(size_t)(k + 2) * nb + nc];
    float v3 = B[(size_t)(k + 3) * nb + nc];
    ushort4 h, l;
    split1(v0, h.x, l.x); split1(v1, h.y, l.y);
    split1(v2, h.z, l.z); split1(v3, h.w, l.w);
    unsigned short* row = Bt + (size_t)n * (3 * K);
    *(ushort4*)&row[k]         = h;
    *(ushort4*)&row[K + k]     = h;
    *(ushort4*)&row[2 * K + k] = l;
}

// ---------------- split-bf16 MFMA GEMM ----------------
// BM=128 fixed. Wave grid WM x WN (WM*WN=4); wave tile (128/WM) x (BN/WN).
// Cfull[m][n] = sum_kk A[m][kk%ka2] * Bt[n][kk]
// n < nsplit -> outPb (bf16, no bias); n >= nsplit -> outR (f32, +bias0+bias1)
__device__ __forceinline__ void glds16(const void* g, void* l)
{
    __builtin_amdgcn_global_load_lds((const __attribute__((address_space(1))) void*)g,
                                     (__attribute__((address_space(3))) void*)l, 16, 0, 0);
}

template<int BN, int WM, int WN>
__global__ __launch_bounds__(256)
void gemm_split(const unsigned short* __restrict__ A, int lda, int ka2,
                const unsigned short* __restrict__ Bt, int keff,
                unsigned short* __restrict__ outPb, float* __restrict__ outR,
                int M, int nsplit, int ldR,
                const float* __restrict__ bias0, const float* __restrict__ bias1)
{
    constexpr int BM  = 128;
    constexpr int WTM = BM / WM;          // wave tile rows
    constexpr int WTN = BN / WN;          // wave tile cols
    constexpr int FJ  = WTM / 16;         // row frags
    constexpr int FI  = WTN / 16;         // col frags
    constexpr int NCH = (BM + BN) / 16;   // 1KB staging chunks per K-step
    constexpr int CPW = NCH / 4;          // chunks per wave

    __shared__ __align__(16) unsigned short sA[BM * 32];
    __shared__ __align__(16) unsigned short sB[BN * 32];
    const int tid = threadIdx.x;
    const int w = tid >> 6, lane = tid & 63;
    const int m0 = blockIdx.y * BM;
    const int n0 = blockIdx.x * BN;
    const int wm = w / WN, wn = w % WN;

    f32x4 acc[FI][FJ] = {};

    // staging chunk setup: chunk = 16 rows x 32 k (1 KB); lane -> (row=lane>>2, k8=lane&3)
    const unsigned short* gp[CPW];
    unsigned short*       lp[CPW];
    bool isa[CPW];
    #pragma unroll
    for (int cc = 0; cc < CPW; ++cc) {
        int c = w * CPW + cc;
        if (c < BM / 16) {
            int gm = m0 + c * 16 + (lane >> 2);
            if (gm >= M) gm = M - 1;
            gp[cc] = A + (size_t)gm * lda + (lane & 3) * 8;
            lp[cc] = &sA[c * 512];
            isa[cc] = true;
        } else {
            int r = (c - BM / 16) * 16 + (lane >> 2);
            gp[cc] = Bt + (size_t)(n0 + r) * keff + (lane & 3) * 8;
            lp[cc] = &sB[(c - BM / 16) * 512];
            isa[cc] = false;
        }
    }

    const int rA = wm * WTM + (lane & 15);
    const int rB = wn * WTN + (lane & 15);
    const int koff = (lane >> 4) * 8;

    for (int kk = 0; kk < keff; kk += 32) {
        const int kA = (kk >= ka2) ? (kk - ka2) : kk;
        #pragma unroll
        for (int cc = 0; cc < CPW; ++cc)
            glds16(gp[cc] + (isa[cc] ? kA : kk), lp[cc]);
        __syncthreads();
        bf16x8 av[FJ], bv[FI];
        #pragma unroll
        for (int f = 0; f < FI; ++f)
            bv[f] = *(const bf16x8*)&sB[(rB + f * 16) * 32 + koff];
        #pragma unroll
        for (int f = 0; f < FJ; ++f)
            av[f] = *(const bf16x8*)&sA[(rA + f * 16) * 32 + koff];
        #pragma unroll
        for (int fj = 0; fj < FJ; ++fj)
            #pragma unroll
            for (int fi = 0; fi < FI; ++fi)
                acc[fi][fj] = __builtin_amdgcn_mfma_f32_16x16x32_bf16(
                    bv[fi], av[fj], acc[fi][fj], 0, 0, 0);
        __syncthreads();
    }

    // D of mfma(bv, av): col(lane&15) = C-row (m), row((lane>>4)*4+reg) = C-col (n)
    const int lrow = lane & 15;
    const int lcol = (lane >> 4) << 2;
    #pragma unroll
    for (int fj = 0; fj < FJ; ++fj) {
        int row = m0 + wm * WTM + fj * 16 + lrow;
        if (row >= M) continue;
        #pragma unroll
        for (int fi = 0; fi < FI; ++fi) {
            int col = n0 + wn * WTN + fi * 16 + lcol;
            f32x4 v = acc[fi][fj];
            if (col < nsplit) {
                ushort4 o;
                o.x = f2b(v[0]); o.y = f2b(v[1]); o.z = f2b(v[2]); o.w = f2b(v[3]);
                *(ushort4*)&outPb[(size_t)row * nsplit + col] = o;
            } else {
                int c = col - nsplit;
                const float4 g0 = *(const float4*)&bias0[c];
                const float4 g1 = *(const float4*)&bias1[c];
                v[0] += g0.x + g1.x; v[1] += g0.y + g1.y;
                v[2] += g0.z + g1.z; v[3] += g0.w + g1.w;
                *(f32x4*)&outR[(size_t)row * ldR + c] = v;
            }
        }
    }
}

// ---------------- per-node attention scores (bf16 h), 4 heads ----------------
__global__ __launch_bounds__(256)
void scores_h4(const unsigned short* __restrict__ h, const float* __restrict__ a_src,
               const float* __restrict__ a_dst, float* __restrict__ s_src,
               float* __restrict__ s_dst)
{
    const int n = blockIdx.x;
    const int w = threadIdx.x >> 6;
    const int lane = threadIdx.x & 63;
    ushort4 u = *(const ushort4*)&h[(size_t)n * C1 + w * D1 + lane * 4];
    float4 as = ((const float4*)&a_src[w * D1])[lane];
    float4 ad = ((const float4*)&a_dst[w * D1])[lane];
    float vx = b2f(u.x), vy = b2f(u.y), vz = b2f(u.z), vw = b2f(u.w);
    float ss = vx * as.x + vy * as.y + vz * as.z + vw * as.w;
    float sd = vx * ad.x + vy * ad.y + vz * ad.z + vw * ad.w;
    #pragma unroll
    for (int off = 32; off; off >>= 1) {
        ss += __shfl_xor(ss, off);
        sd += __shfl_xor(sd, off);
    }
    if (lane == 0) { s_src[n * NH1 + w] = ss; s_dst[n * NH1 + w] = sd; }
}

// ---------------- per-node attention scores (bf16 h), 1 head ----------------
__global__ __launch_bounds__(256)
void scores_h1(const unsigned short* __restrict__ h, const float* __restrict__ a_src,
               const float* __restrict__ a_dst, float* __restrict__ s_src,
               float* __restrict__ s_dst)
{
    const int n = blockIdx.x * 4 + (threadIdx.x >> 6);
    if (n >= NN) return;
    const int lane = threadIdx.x & 63;
    ushort4 u = *(const ushort4*)&h[(size_t)n * D2 + lane * 4];
    float4 as = ((const float4*)a_src)[lane];
    float4 ad = ((const float4*)a_dst)[lane];
    float vx = b2f(u.x), vy = b2f(u.y), vz = b2f(u.z), vw = b2f(u.w);
    float ss = vx * as.x + vy * as.y + vz * as.z + vw * as.w;
    float sd = vx * ad.x + vy * ad.y + vz * ad.z + vw * ad.w;
    #pragma unroll
    for (int off = 32; off; off >>= 1) {
        ss += __shfl_xor(ss, off);
        sd += __shfl_xor(sd, off);
    }
    if (lane == 0) { s_src[n] = ss; s_dst[n] = sd; }
}

// ---------------- CSR build ----------------
__global__ void count_deg(const int* __restrict__ dstp, int* __restrict__ cnt)
{
    int e = blockIdx.x * 256 + threadIdx.x;
    if (e >= ETOT) return;
    int d = (e < EE) ? dstp[e] : (e - EE);
    atomicAdd(&cnt[d], 1);
}

__global__ __launch_bounds__(1024)
void scan_kernel(const int* __restrict__ cnt, int* __restrict__ row_ptr)
{
    __shared__ int part[1024];
    const int t = threadIdx.x;
    int local[10];
    int s = 0;
    #pragma unroll
    for (int j = 0; j < 10; ++j) {
        int idx = t * 10 + j;
        local[j] = s;
        s += (idx < NN) ? cnt[idx] : 0;
    }
    part[t] = s;
    __syncthreads();
    for (int off = 1; off < 1024; off <<= 1) {
        int v = (t >= off) ? part[t - off] : 0;
        __syncthreads();
        part[t] += v;
        __syncthreads();
    }
    int prefix = (t > 0) ? part[t - 1] : 0;
    #pragma unroll
    for (int j = 0; j < 10; ++j) {
        int idx = t * 10 + j;
        if (idx < NN) row_ptr[idx] = prefix + local[j];
    }
    if (t == 0) row_ptr[NN] = ETOT;
}

__global__ void scatter_edges(const int* __restrict__ srcp, const int* __restrict__ dstp,
                              const int* __restrict__ row_ptr, int* __restrict__ fill,
                              int* __restrict__ csr_src, int* __restrict__ csr_eid)
{
    int e = blockIdx.x * 256 + threadIdx.x;
    if (e >= ETOT) return;
    int s, d;
    if (e < EE) { s = srcp[e]; d = dstp[e]; } else { s = d = e - EE; }
    int pos = row_ptr[d] + atomicAdd(&fill[d], 1);
    csr_src[pos] = s;
    csr_eid[pos] = e;
}

// -------- fused layer-1: segment softmax (alpha1 -> d_out) + aggregation + residual
//          + ELU + hi|lo bf16 split (in place over base_in) --------
// 4 waves; wave w == head w. Phase-2 dim range of wave w is exactly head w,
// so m/z stay in registers; no LDS handoff needed.
__global__ __launch_bounds__(256)
void aggregate1(const unsigned short* __restrict__ h1b, const float* __restrict__ s_src,
                const float* __restrict__ s_dst,
                const int* __restrict__ row_ptr, const int* __restrict__ csr_src,
                const int* __restrict__ csr_eid, const float* __restrict__ base_in,
                unsigned short* __restrict__ a2stk, float* __restrict__ alpha_out)
{
    const int n = blockIdx.x;
    const int t = threadIdx.x;          // dims 4t..4t+3; head = t>>6
    const int h = t >> 6;
    const int lane = t & 63;
    const int start = row_ptr[n], end = row_ptr[n + 1];
    const float sd = s_dst[n * NH1 + h];

    // phase 1: segment max + sum for head h (lane-strided), write alpha1
    float m = -1e30f;
    for (int i = start + lane; i < end; i += 64) {
        float sc = s_src[csr_src[i] * NH1 + h] + sd;
        sc = sc > 0.f ? sc : 0.2f * sc;
        m = fmaxf(m, sc);
    }
    #pragma unroll
    for (int off = 32; off; off >>= 1) m = fmaxf(m, __shfl_xor(m, off));
    float z = 0.f;
    for (int i = start + lane; i < end; i += 64) {
        float sc = s_src[csr_src[i] * NH1 + h] + sd;
        sc = sc > 0.f ? sc : 0.2f * sc;
        z += __expf(sc - m);
    }
    #pragma unroll
    for (int off = 32; off; off >>= 1) z += __shfl_xor(z, off);
    const float invz = 1.f / (z + 1e-16f);
    for (int i = start + lane; i < end; i += 64) {
        float sc = s_src[csr_src[i] * NH1 + h] + sd;
        sc = sc > 0.f ? sc : 0.2f * sc;
        alpha_out[(size_t)csr_eid[i] * NH1 + h] = __expf(sc - m) * invz;
    }

    // phase 2: aggregation (alpha recomputed per edge, wave-uniform scalar path)
    float4 base = *(const float4*)&base_in[(size_t)n * C1 + t * 4];
    float4 acc = make_float4(0.f, 0.f, 0.f, 0.f);
    for (int i = start; i < end; ++i) {
        const int s = csr_src[i];
        float sc = s_src[s * NH1 + h] + sd;
        sc = sc > 0.f ? sc : 0.2f * sc;
        const float a = __expf(sc - m) * invz;
        ushort4 v = *(const ushort4*)&h1b[(size_t)s * C1 + t * 4];
        acc.x += a * b2f(v.x); acc.y += a * b2f(v.y);
        acc.z += a * b2f(v.z); acc.w += a * b2f(v.w);
    }
    float4 r;
    r.x = acc.x + base.x; r.y = acc.y + base.y;
    r.z = acc.z + base.z; r.w = acc.w + base.w;
    r.x = r.x > 0.f ? r.x : expm1f(r.x);
    r.y = r.y > 0.f ? r.y : expm1f(r.y);
    r.z = r.z > 0.f ? r.z : expm1f(r.z);
    r.w = r.w > 0.f ? r.w : expm1f(r.w);
    __syncthreads();    // all base_in reads done before in-place overwrite
    ushort4 hi, lo;
    split1(r.x, hi.x, lo.x); split1(r.y, hi.y, lo.y);
    split1(r.z, hi.z, lo.z); split1(r.w, hi.w, lo.w);
    unsigned short* row = a2stk + (size_t)n * (2 * C1);
    *(ushort4*)&row[t * 4]      = hi;
    *(ushort4*)&row[C1 + t * 4] = lo;
}

// -------- fused layer-2: segment softmax + aggregation + residual -> final out --------
__global__ __launch_bounds__(64)
void aggregate2(const unsigned short* __restrict__ h2b, const float* __restrict__ s_src,
                const float* __restrict__ s_dst,
                const int* __restrict__ row_ptr, const int* __restrict__ csr_src,
                const float* __restrict__ accin, float* __restrict__ out)
{
    const int n = blockIdx.x;
    const int t = threadIdx.x;          // dims 4t..4t+3
    const int start = row_ptr[n], end = row_ptr[n + 1];
    const float sd = s_dst[n];

    float m = -1e30f;
    for (int i = start + t; i < end; i += 64) {
        float sc = s_src[csr_src[i]] + sd;
        sc = sc > 0.f ? sc : 0.2f * sc;
        m = fmaxf(m, sc);
    }
    #pragma unroll
    for (int off = 32; off; off >>= 1) m = fmaxf(m, __shfl_xor(m, off));
    float z = 0.f;
    for (int i = start + t; i < end; i += 64) {
        float sc = s_src[csr_src[i]] + sd;
        sc = sc > 0.f ? sc : 0.2f * sc;
        z += __expf(sc - m);
    }
    #pragma unroll
    for (int off = 32; off; off >>= 1) z += __shfl_xor(z, off);
    const float invz = 1.f / (z + 1e-16f);

    float4 acc = make_float4(0.f, 0.f, 0.f, 0.f);
    for (int i = start; i < end; ++i) {
        const int s = csr_src[i];
        float sc = s_src[s] + sd;
        sc = sc > 0.f ? sc : 0.2f * sc;
        const float a = __expf(sc - m) * invz;
        ushort4 v = *(const ushort4*)&h2b[(size_t)s * D2 + t * 4];
        acc.x += a * b2f(v.x); acc.y += a * b2f(v.y);
        acc.z += a * b2f(v.z); acc.w += a * b2f(v.w);
    }
    float4 base = *(const float4*)&accin[(size_t)n * D2 + t * 4];
    float4 r;
    r.x = acc.x + base.x; r.y = acc.y + base.y;
    r.z = acc.z + base.z; r.w = acc.w + base.w;
    *(float4*)&out[(size_t)n * D2 + t * 4] = r;
}

extern "C" void kernel_launch(void* const* d_in, const int* in_sizes, int n_in,
                              void* d_out, int out_size, void* d_ws, size_t ws_size,
                              hipStream_t stream)
{
    const float* x        = (const float*)d_in[0];
    const int*   ei       = (const int*)  d_in[1];
    const float* W1       = (const float*)d_in[2];
    const float* att_src1 = (const float*)d_in[3];
    const float* att_dst1 = (const float*)d_in[4];
    const float* b1       = (const float*)d_in[5];
    const float* lin1_W   = (const float*)d_in[6];
    const float* lin1_b   = (const float*)d_in[7];
    const float* W2       = (const float*)d_in[8];
    const float* att_src2 = (const float*)d_in[9];
    const float* att_dst2 = (const float*)d_in[10];
    const float* b2       = (const float*)d_in[11];
    const float* lin2_W   = (const float*)d_in[12];
    const float* lin2_b   = (const float*)d_in[13];
    const int* srcp = ei;
    const int* dstp = ei + EE;

    float* out    = (float*)d_out;
    float* alpha1 = out + (size_t)NN * D2;           // [ETOT,4] region of d_out

    float* fw = (float*)d_ws;
    float* acc1   = fw;   fw += (size_t)NN * C1;     // lin1 residual; becomes A2stk (bf16 hi|lo)
    unsigned short* h1b = (unsigned short*)fw; fw += (size_t)NN * C1 / 2;   // [NN][C1] bf16
    unsigned short* h2b = (unsigned short*)fw; fw += (size_t)NN * D2 / 2;   // [NN][D2] bf16
    float* acc2   = fw;   fw += (size_t)NN * D2;     // lin2 residual
    unsigned short* A1stk = (unsigned short*)fw; fw += (size_t)NN * FIN;            // [NN][2*FIN] bf16
    unsigned short* Bt1   = (unsigned short*)fw; fw += (size_t)2048 * 3 * FIN / 2;  // [2048][384]
    unsigned short* Bt2   = (unsigned short*)fw; fw += (size_t)512 * 3 * C1 / 2;    // [512][3072]
    float* s_src1 = fw;   fw += NN * NH1;
    float* s_dst1 = fw;   fw += NN * NH1;
    float* s_src2 = fw;   fw += NN;
    float* s_dst2 = fw;   fw += NN;
    int* ip      = (int*)fw;
    int* cnt     = ip;    ip += NN;
    int* fill    = ip;    ip += NN;
    int* row_ptr = ip;    ip += NN + 4;
    int* csr_src = ip;    ip += ETOT;
    int* csr_eid = ip;    ip += ETOT;

    unsigned short* A2stk = (unsigned short*)acc1;   // alias: [NN][2*C1] bf16, in-place

    hipMemsetAsync(cnt, 0, 2 * NN * sizeof(int), stream);

    const int mt = (NN + 127) / 128;

    // ---- layer 1 transforms (fused W1|lin1_W), split-bf16 MFMA ----
    split_A<<<(NN * (FIN / 4) + 255) / 256, 256, 0, stream>>>(x, A1stk, NN, FIN);
    split_Bt<<<(2048 * (FIN / 4) + 255) / 256, 256, 0, stream>>>(W1, lin1_W, FIN, C1, 2048, Bt1);
    gemm_split<128, 2, 2><<<dim3(16, mt), 256, 0, stream>>>(
        A1stk, 2 * FIN, 2 * FIN, Bt1, 3 * FIN, h1b, acc1, NN, C1, C1, lin1_b, b1);
    scores_h4<<<NN, 256, 0, stream>>>(h1b, att_src1, att_dst1, s_src1, s_dst1);

    // ---- CSR by destination (shared by both layers) ----
    count_deg<<<(ETOT + 255) / 256, 256, 0, stream>>>(dstp, cnt);
    scan_kernel<<<1, 1024, 0, stream>>>(cnt, row_ptr);
    scatter_edges<<<(ETOT + 255) / 256, 256, 0, stream>>>(srcp, dstp, row_ptr, fill,
                                                          csr_src, csr_eid);

    // ---- fused layer-1 softmax+aggregate+ELU+split (alpha1 -> d_out) ----
    aggregate1<<<NN, 256, 0, stream>>>(h1b, s_src1, s_dst1, row_ptr, csr_src, csr_eid,
                                       acc1, A2stk, alpha1);

    // ---- layer 2 transforms (fused W2|lin2_W), split-bf16 MFMA, BN=64 for occupancy ----
    split_Bt<<<(512 * (C1 / 4) + 255) / 256, 256, 0, stream>>>(W2, lin2_W, C1, D2, 512, Bt2);
    gemm_split<64, 4, 1><<<dim3(8, mt), 256, 0, stream>>>(
        A2stk, 2 * C1, 2 * C1, Bt2, 3 * C1, h2b, acc2, NN, D2, D2, lin2_b, b2);

    // ---- fused layer-2 softmax+aggregate -> out ----
    scores_h1<<<(NN + 3) / 4, 256, 0, stream>>>(h2b, att_src2, att_dst2, s_src2, s_dst2);
    aggregate2<<<NN, 64, 0, stream>>>(h2b, s_src2, s_dst2, row_ptr, csr_src, acc2, out);
}

// Round 6
// 236.285 us; speedup vs baseline: 2.3022x; 1.1375x over previous
//
#include <hip/hip_runtime.h>
#include <hip/hip_bf16.h>
#include <math.h>

#define NN   10000
#define EE   160000
#define ETOT 170000
#define FIN  128
#define C1   1024   // H1*D1
#define NH1  4
#define D1   256
#define D2   256

typedef __attribute__((ext_vector_type(8))) short bf16x8;
typedef __attribute__((ext_vector_type(4))) float f32x4;

// ---------------- bf16 helpers ----------------
__device__ __forceinline__ float b2f(unsigned short u)
{
    union { unsigned int i; float f; } c; c.i = (unsigned int)u << 16; return c.f;
}
__device__ __forceinline__ unsigned short f2b(float x)
{
    return __builtin_bit_cast(unsigned short, __float2bfloat16(x));
}
__device__ __forceinline__ void split1(float x, unsigned short &h, unsigned short &l)
{
    __hip_bfloat16 hb = __float2bfloat16(x);
    float r = x - __bfloat162float(hb);
    h = __builtin_bit_cast(unsigned short, hb);
    l = __builtin_bit_cast(unsigned short, __float2bfloat16(r));
}

// Astk[m][0..K-1] = hi, [K..2K-1] = lo
__global__ __launch_bounds__(256)
void split_A(const float* __restrict__ X, unsigned short* __restrict__ A2, int M, int K)
{
    int idx = blockIdx.x * 256 + threadIdx.x;
    int kq4 = K >> 2;
    if (idx >= M * kq4) return;
    int m = idx / kq4, kq = idx % kq4;
    float4 v = *(const float4*)&X[(size_t)m * K + kq * 4];
    ushort4 h, l;
    split1(v.x, h.x, l.x); split1(v.y, h.y, l.y);
    split1(v.z, h.z, l.z); split1(v.w, h.w, l.w);
    unsigned short* row = A2 + (size_t)m * (2 * K);
    *(ushort4*)&row[kq * 4]     = h;
    *(ushort4*)&row[K + kq * 4] = l;
}

// Bt[n][0..K-1] = hi, [K..2K-1] = hi, [2K..3K-1] = lo ; n stacked over {B0, B1}
__global__ __launch_bounds__(256)
void split_Bt(const float* __restrict__ B0, const float* __restrict__ B1,
              int K, int N0, int Ntot, unsigned short* __restrict__ Bt)
{
    int idx = blockIdx.x * 256 + threadIdx.x;
    int total = Ntot * (K >> 2);
    if (idx >= total) return;
    int n = idx % Ntot;
    int kq = idx / Ntot;
    int k = kq * 4;
    const float* B; int nc, nb;
    if (n < N0) { B = B0; nc = n; nb = N0; }
    else        { B = B1; nc = n - N0; nb = Ntot - N0; }
    float v0 = B[(size_t)(k + 0) * nb + nc];
    float v1 = B[(size_t)(k + 1) * nb + nc];
    float v2 = B[(size_t)(k + 2) * nb + nc];
    float v3 = B[(size_t)(k + 3) * nb + nc];
    ushort4 h, l;
    split1(v0, h.x, l.x); split1(v1, h.y, l.y);
    split1(v2, h.z, l.z); split1(v3, h.w, l.w);
    unsigned short* row = Bt + (size_t)n * (3 * K);
    *(ushort4*)&row[k]         = h;
    *(ushort4*)&row[K + k]     = h;
    *(ushort4*)&row[2 * K + k] = l;
}

// ---------------- split-bf16 MFMA GEMM, 2-phase dbuf + LDS swizzle + XCD chunking ------
// Cfull[m][n] = sum_kk A[m][kk%ka2] * Bt[n][kk]
// n < nsplit -> outPb (bf16, no bias); n >= nsplit -> outR (f32, +bias0+bias1)
__device__ __forceinline__ void glds16(const void* g, void* l)
{
    __builtin_amdgcn_global_load_lds((const __attribute__((address_space(1))) void*)g,
                                     (__attribute__((address_space(3))) void*)l, 16, 0, 0);
}

template<int BN, int WM, int WN, int BK>
__global__ __launch_bounds__(256)
void gemm_split(const unsigned short* __restrict__ A, int lda, int ka2,
                const unsigned short* __restrict__ Bt, int keff,
                unsigned short* __restrict__ outPb, float* __restrict__ outR,
                int M, int nsplit, int ldR, int ntn,
                const float* __restrict__ bias0, const float* __restrict__ bias1)
{
    constexpr int BM   = 128;
    constexpr int WTM  = BM / WM,  WTN = BN / WN;
    constexpr int FJ   = WTM / 16, FI  = WTN / 16;
    constexpr int KS   = BK / 32;           // 32-wide k-slices per step
    constexpr int SLOTS = BK / 8;           // 16B slots per LDS row
    constexpr int SMASK = SLOTS - 1;
    constexpr int SWSH  = (BK == 32) ? 1 : 0;   // swizzle shift (bank-phase aware)
    constexpr int RPC  = 512 / BK;          // rows per 1KB staging chunk
    constexpr int ACH  = BM / RPC;
    constexpr int NCH  = (BM + BN) / RPC;
    constexpr int CPW  = NCH / 4;           // chunks per wave
    constexpr int ABUF = BM * BK, BBUF = BN * BK;

    __shared__ __align__(16) unsigned short sA[2 * ABUF];
    __shared__ __align__(16) unsigned short sB[2 * BBUF];

    const int tid = threadIdx.x;
    const int w = tid >> 6, lane = tid & 63;

    // XCD-chunked bijective swizzle (gridDim.x % 8 == 0 guaranteed by launch)
    const int cpx = gridDim.x >> 3;
    const int t0  = (blockIdx.x & 7) * cpx + (blockIdx.x >> 3);
    const int m0 = (t0 / ntn) * BM;
    const int n0 = (t0 % ntn) * BN;
    const int wm = w / WN, wn = w % WN;

    f32x4 acc[FI][FJ] = {};

    // staging setup: chunk = RPC rows x BK elems (1KB); lane -> (row=lane/SLOTS, slot)
    // source column pre-swizzled so LDS-linear write + swizzled read = involution
    const unsigned short* gp[CPW];
    int lofs[CPW];
    bool isa[CPW];
    {
        const int r  = lane / SLOTS;
        const int sl = lane % SLOTS;
        const int ssl = sl ^ ((r >> SWSH) & SMASK);
        #pragma unroll
        for (int cc = 0; cc < CPW; ++cc) {
            int c = w * CPW + cc;
            if (c < ACH) {
                int gm = m0 + c * RPC + r; if (gm >= M) gm = M - 1;
                gp[cc]   = A + (size_t)gm * lda + ssl * 8;
                lofs[cc] = c * 512;
                isa[cc]  = true;
            } else {
                int gn = n0 + (c - ACH) * RPC + r;
                gp[cc]   = Bt + (size_t)gn * keff + ssl * 8;
                lofs[cc] = (c - ACH) * 512;
                isa[cc]  = false;
            }
        }
    }

    const int rAl = wm * WTM + (lane & 15);
    const int rBl = wn * WTN + (lane & 15);
    const int koff = (lane >> 4) * 8;
    const int nit = keff / BK;
    int cur = 0;

    // prologue: stage tile 0 into buffer 0
    #pragma unroll
    for (int cc = 0; cc < CPW; ++cc)
        glds16(gp[cc], (isa[cc] ? sA : sB) + lofs[cc]);
    __syncthreads();

    for (int it = 0; it < nit; ++it) {
        // stage next tile into the other buffer (overlaps with compute below)
        if (it + 1 < nit) {
            int kn = (it + 1) * BK;
            int kAn = (kn >= ka2) ? (kn - ka2) : kn;
            #pragma unroll
            for (int cc = 0; cc < CPW; ++cc) {
                unsigned short* dst = (isa[cc] ? sA + (cur ^ 1) * ABUF
                                               : sB + (cur ^ 1) * BBUF) + lofs[cc];
                glds16(gp[cc] + (isa[cc] ? kAn : kn), dst);
            }
        }
        // compute current tile
        const unsigned short* cA = sA + cur * ABUF;
        const unsigned short* cB = sB + cur * BBUF;
        #pragma unroll
        for (int ks = 0; ks < KS; ++ks) {
            const int sIdx = (ks * 32 + koff) >> 3;
            bf16x8 av[FJ], bv[FI];
            #pragma unroll
            for (int f = 0; f < FI; ++f) {
                int row = rBl + f * 16;
                bv[f] = *(const bf16x8*)&cB[row * BK + ((sIdx ^ ((row >> SWSH) & SMASK)) << 3)];
            }
            #pragma unroll
            for (int f = 0; f < FJ; ++f) {
                int row = rAl + f * 16;
                av[f] = *(const bf16x8*)&cA[row * BK + ((sIdx ^ ((row >> SWSH) & SMASK)) << 3)];
            }
            #pragma unroll
            for (int fj = 0; fj < FJ; ++fj)
                #pragma unroll
                for (int fi = 0; fi < FI; ++fi)
                    acc[fi][fj] = __builtin_amdgcn_mfma_f32_16x16x32_bf16(
                        bv[fi], av[fj], acc[fi][fj], 0, 0, 0);
        }
        __syncthreads();   // drains staged loads (vmcnt) + readers (lgkm); swap
        cur ^= 1;
    }

    // D of mfma(bv, av): col(lane&15) = C-row (m), row((lane>>4)*4+reg) = C-col (n)
    const int lrow = lane & 15;
    const int lcol = (lane >> 4) << 2;
    #pragma unroll
    for (int fj = 0; fj < FJ; ++fj) {
        int row = m0 + wm * WTM + fj * 16 + lrow;
        if (row >= M) continue;
        #pragma unroll
        for (int fi = 0; fi < FI; ++fi) {
            int col = n0 + wn * WTN + fi * 16 + lcol;
            f32x4 v = acc[fi][fj];
            if (col < nsplit) {
                ushort4 o;
                o.x = f2b(v[0]); o.y = f2b(v[1]); o.z = f2b(v[2]); o.w = f2b(v[3]);
                *(ushort4*)&outPb[(size_t)row * nsplit + col] = o;
            } else {
                int c = col - nsplit;
                const float4 g0 = *(const float4*)&bias0[c];
                const float4 g1 = *(const float4*)&bias1[c];
                v[0] += g0.x + g1.x; v[1] += g0.y + g1.y;
                v[2] += g0.z + g1.z; v[3] += g0.w + g1.w;
                *(f32x4*)&outR[(size_t)row * ldR + c] = v;
            }
        }
    }
}

// ---------------- per-node attention scores (bf16 h), 4 heads ----------------
__global__ __launch_bounds__(256)
void scores_h4(const unsigned short* __restrict__ h, const float* __restrict__ a_src,
               const float* __restrict__ a_dst, float* __restrict__ s_src,
               float* __restrict__ s_dst)
{
    const int n = blockIdx.x;
    const int w = threadIdx.x >> 6;
    const int lane = threadIdx.x & 63;
    ushort4 u = *(const ushort4*)&h[(size_t)n * C1 + w * D1 + lane * 4];
    float4 as = ((const float4*)&a_src[w * D1])[lane];
    float4 ad = ((const float4*)&a_dst[w * D1])[lane];
    float vx = b2f(u.x), vy = b2f(u.y), vz = b2f(u.z), vw = b2f(u.w);
    float ss = vx * as.x + vy * as.y + vz * as.z + vw * as.w;
    float sd = vx * ad.x + vy * ad.y + vz * ad.z + vw * ad.w;
    #pragma unroll
    for (int off = 32; off; off >>= 1) {
        ss += __shfl_xor(ss, off);
        sd += __shfl_xor(sd, off);
    }
    if (lane == 0) { s_src[n * NH1 + w] = ss; s_dst[n * NH1 + w] = sd; }
}

// ---------------- per-node attention scores (bf16 h), 1 head ----------------
__global__ __launch_bounds__(256)
void scores_h1(const unsigned short* __restrict__ h, const float* __restrict__ a_src,
               const float* __restrict__ a_dst, float* __restrict__ s_src,
               float* __restrict__ s_dst)
{
    const int n = blockIdx.x * 4 + (threadIdx.x >> 6);
    if (n >= NN) return;
    const int lane = threadIdx.x & 63;
    ushort4 u = *(const ushort4*)&h[(size_t)n * D2 + lane * 4];
    float4 as = ((const float4*)a_src)[lane];
    float4 ad = ((const float4*)a_dst)[lane];
    float vx = b2f(u.x), vy = b2f(u.y), vz = b2f(u.z), vw = b2f(u.w);
    float ss = vx * as.x + vy * as.y + vz * as.z + vw * as.w;
    float sd = vx * ad.x + vy * ad.y + vz * ad.z + vw * ad.w;
    #pragma unroll
    for (int off = 32; off; off >>= 1) {
        ss += __shfl_xor(ss, off);
        sd += __shfl_xor(sd, off);
    }
    if (lane == 0) { s_src[n] = ss; s_dst[n] = sd; }
}

// ---------------- CSR build ----------------
__global__ void count_deg(const int* __restrict__ dstp, int* __restrict__ cnt)
{
    int e = blockIdx.x * 256 + threadIdx.x;
    if (e >= ETOT) return;
    int d = (e < EE) ? dstp[e] : (e - EE);
    atomicAdd(&cnt[d], 1);
}

__global__ __launch_bounds__(1024)
void scan_kernel(const int* __restrict__ cnt, int* __restrict__ row_ptr)
{
    __shared__ int part[1024];
    const int t = threadIdx.x;
    int local[10];
    int s = 0;
    #pragma unroll
    for (int j = 0; j < 10; ++j) {
        int idx = t * 10 + j;
        local[j] = s;
        s += (idx < NN) ? cnt[idx] : 0;
    }
    part[t] = s;
    __syncthreads();
    for (int off = 1; off < 1024; off <<= 1) {
        int v = (t >= off) ? part[t - off] : 0;
        __syncthreads();
        part[t] += v;
        __syncthreads();
    }
    int prefix = (t > 0) ? part[t - 1] : 0;
    #pragma unroll
    for (int j = 0; j < 10; ++j) {
        int idx = t * 10 + j;
        if (idx < NN) row_ptr[idx] = prefix + local[j];
    }
    if (t == 0) row_ptr[NN] = ETOT;
}

__global__ void scatter_edges(const int* __restrict__ srcp, const int* __restrict__ dstp,
                              const int* __restrict__ row_ptr, int* __restrict__ fill,
                              int* __restrict__ csr_src, int* __restrict__ csr_eid)
{
    int e = blockIdx.x * 256 + threadIdx.x;
    if (e >= ETOT) return;
    int s, d;
    if (e < EE) { s = srcp[e]; d = dstp[e]; } else { s = d = e - EE; }
    int pos = row_ptr[d] + atomicAdd(&fill[d], 1);
    csr_src[pos] = s;
    csr_eid[pos] = e;
}

// -------- fused layer-1: segment softmax (alpha1 -> d_out) + aggregation + residual
//          + ELU + hi|lo bf16 split (in place over base_in) --------
__global__ __launch_bounds__(256)
void aggregate1(const unsigned short* __restrict__ h1b, const float* __restrict__ s_src,
                const float* __restrict__ s_dst,
                const int* __restrict__ row_ptr, const int* __restrict__ csr_src,
                const int* __restrict__ csr_eid, const float* __restrict__ base_in,
                unsigned short* __restrict__ a2stk, float* __restrict__ alpha_out)
{
    const int n = blockIdx.x;
    const int t = threadIdx.x;          // dims 4t..4t+3; head = t>>6
    const int h = t >> 6;
    const int lane = t & 63;
    const int start = row_ptr[n], end = row_ptr[n + 1];
    const float sd = s_dst[n * NH1 + h];

    float m = -1e30f;
    for (int i = start + lane; i < end; i += 64) {
        float sc = s_src[csr_src[i] * NH1 + h] + sd;
        sc = sc > 0.f ? sc : 0.2f * sc;
        m = fmaxf(m, sc);
    }
    #pragma unroll
    for (int off = 32; off; off >>= 1) m = fmaxf(m, __shfl_xor(m, off));
    float z = 0.f;
    for (int i = start + lane; i < end; i += 64) {
        float sc = s_src[csr_src[i] * NH1 + h] + sd;
        sc = sc > 0.f ? sc : 0.2f * sc;
        z += __expf(sc - m);
    }
    #pragma unroll
    for (int off = 32; off; off >>= 1) z += __shfl_xor(z, off);
    const float invz = 1.f / (z + 1e-16f);
    for (int i = start + lane; i < end; i += 64) {
        float sc = s_src[csr_src[i] * NH1 + h] + sd;
        sc = sc > 0.f ? sc : 0.2f * sc;
        alpha_out[(size_t)csr_eid[i] * NH1 + h] = __expf(sc - m) * invz;
    }

    float4 base = *(const float4*)&base_in[(size_t)n * C1 + t * 4];
    float4 acc = make_float4(0.f, 0.f, 0.f, 0.f);
    for (int i = start; i < end; ++i) {
        const int s = csr_src[i];
        float sc = s_src[s * NH1 + h] + sd;
        sc = sc > 0.f ? sc : 0.2f * sc;
        const float a = __expf(sc - m) * invz;
        ushort4 v = *(const ushort4*)&h1b[(size_t)s * C1 + t * 4];
        acc.x += a * b2f(v.x); acc.y += a * b2f(v.y);
        acc.z += a * b2f(v.z); acc.w += a * b2f(v.w);
    }
    float4 r;
    r.x = acc.x + base.x; r.y = acc.y + base.y;
    r.z = acc.z + base.z; r.w = acc.w + base.w;
    r.x = r.x > 0.f ? r.x : expm1f(r.x);
    r.y = r.y > 0.f ? r.y : expm1f(r.y);
    r.z = r.z > 0.f ? r.z : expm1f(r.z);
    r.w = r.w > 0.f ? r.w : expm1f(r.w);
    __syncthreads();    // all base_in reads done before in-place overwrite
    ushort4 hi, lo;
    split1(r.x, hi.x, lo.x); split1(r.y, hi.y, lo.y);
    split1(r.z, hi.z, lo.z); split1(r.w, hi.w, lo.w);
    unsigned short* row = a2stk + (size_t)n * (2 * C1);
    *(ushort4*)&row[t * 4]      = hi;
    *(ushort4*)&row[C1 + t * 4] = lo;
}

// -------- fused layer-2: segment softmax + aggregation + residual -> final out --------
__global__ __launch_bounds__(64)
void aggregate2(const unsigned short* __restrict__ h2b, const float* __restrict__ s_src,
                const float* __restrict__ s_dst,
                const int* __restrict__ row_ptr, const int* __restrict__ csr_src,
                const float* __restrict__ accin, float* __restrict__ out)
{
    const int n = blockIdx.x;
    const int t = threadIdx.x;
    const int start = row_ptr[n], end = row_ptr[n + 1];
    const float sd = s_dst[n];

    float m = -1e30f;
    for (int i = start + t; i < end; i += 64) {
        float sc = s_src[csr_src[i]] + sd;
        sc = sc > 0.f ? sc : 0.2f * sc;
        m = fmaxf(m, sc);
    }
    #pragma unroll
    for (int off = 32; off; off >>= 1) m = fmaxf(m, __shfl_xor(m, off));
    float z = 0.f;
    for (int i = start + t; i < end; i += 64) {
        float sc = s_src[csr_src[i]] + sd;
        sc = sc > 0.f ? sc : 0.2f * sc;
        z += __expf(sc - m);
    }
    #pragma unroll
    for (int off = 32; off; off >>= 1) z += __shfl_xor(z, off);
    const float invz = 1.f / (z + 1e-16f);

    float4 acc = make_float4(0.f, 0.f, 0.f, 0.f);
    for (int i = start; i < end; ++i) {
        const int s = csr_src[i];
        float sc = s_src[s] + sd;
        sc = sc > 0.f ? sc : 0.2f * sc;
        const float a = __expf(sc - m) * invz;
        ushort4 v = *(const ushort4*)&h2b[(size_t)s * D2 + t * 4];
        acc.x += a * b2f(v.x); acc.y += a * b2f(v.y);
        acc.z += a * b2f(v.z); acc.w += a * b2f(v.w);
    }
    float4 base = *(const float4*)&accin[(size_t)n * D2 + t * 4];
    float4 r;
    r.x = acc.x + base.x; r.y = acc.y + base.y;
    r.z = acc.z + base.z; r.w = acc.w + base.w;
    *(float4*)&out[(size_t)n * D2 + t * 4] = r;
}

extern "C" void kernel_launch(void* const* d_in, const int* in_sizes, int n_in,
                              void* d_out, int out_size, void* d_ws, size_t ws_size,
                              hipStream_t stream)
{
    const float* x        = (const float*)d_in[0];
    const int*   ei       = (const int*)  d_in[1];
    const float* W1       = (const float*)d_in[2];
    const float* att_src1 = (const float*)d_in[3];
    const float* att_dst1 = (const float*)d_in[4];
    const float* b1       = (const float*)d_in[5];
    const float* lin1_W   = (const float*)d_in[6];
    const float* lin1_b   = (const float*)d_in[7];
    const float* W2       = (const float*)d_in[8];
    const float* att_src2 = (const float*)d_in[9];
    const float* att_dst2 = (const float*)d_in[10];
    const float* b2       = (const float*)d_in[11];
    const float* lin2_W   = (const float*)d_in[12];
    const float* lin2_b   = (const float*)d_in[13];
    const int* srcp = ei;
    const int* dstp = ei + EE;

    float* out    = (float*)d_out;
    float* alpha1 = out + (size_t)NN * D2;           // [ETOT,4] region of d_out

    float* fw = (float*)d_ws;
    float* acc1   = fw;   fw += (size_t)NN * C1;     // lin1 residual; becomes A2stk (bf16 hi|lo)
    unsigned short* h1b = (unsigned short*)fw; fw += (size_t)NN * C1 / 2;   // [NN][C1] bf16
    unsigned short* h2b = (unsigned short*)fw; fw += (size_t)NN * D2 / 2;   // [NN][D2] bf16
    float* acc2   = fw;   fw += (size_t)NN * D2;     // lin2 residual
    unsigned short* A1stk = (unsigned short*)fw; fw += (size_t)NN * FIN;            // [NN][2*FIN] bf16
    unsigned short* Bt1   = (unsigned short*)fw; fw += (size_t)2048 * 3 * FIN / 2;  // [2048][384]
    unsigned short* Bt2   = (unsigned short*)fw; fw += (size_t)512 * 3 * C1 / 2;    // [512][3072]
    float* s_src1 = fw;   fw += NN * NH1;
    float* s_dst1 = fw;   fw += NN * NH1;
    float* s_src2 = fw;   fw += NN;
    float* s_dst2 = fw;   fw += NN;
    int* ip      = (int*)fw;
    int* cnt     = ip;    ip += NN;
    int* fill    = ip;    ip += NN;
    int* row_ptr = ip;    ip += NN + 4;
    int* csr_src = ip;    ip += ETOT;
    int* csr_eid = ip;    ip += ETOT;

    unsigned short* A2stk = (unsigned short*)acc1;   // alias: [NN][2*C1] bf16, in-place

    hipMemsetAsync(cnt, 0, 2 * NN * sizeof(int), stream);

    const int mt = (NN + 127) / 128;                 // 79 m-panels

    // ---- layer 1 transforms (fused W1|lin1_W), split-bf16 MFMA ----
    split_A<<<(NN * (FIN / 4) + 255) / 256, 256, 0, stream>>>(x, A1stk, NN, FIN);
    split_Bt<<<(2048 * (FIN / 4) + 255) / 256, 256, 0, stream>>>(W1, lin1_W, FIN, C1, 2048, Bt1);
    gemm_split<128, 2, 2, 32><<<mt * 16, 256, 0, stream>>>(
        A1stk, 2 * FIN, 2 * FIN, Bt1, 3 * FIN, h1b, acc1, NN, C1, C1, 16, lin1_b, b1);
    scores_h4<<<NN, 256, 0, stream>>>(h1b, att_src1, att_dst1, s_src1, s_dst1);

    // ---- CSR by destination (shared by both layers) ----
    count_deg<<<(ETOT + 255) / 256, 256, 0, stream>>>(dstp, cnt);
    scan_kernel<<<1, 1024, 0, stream>>>(cnt, row_ptr);
    scatter_edges<<<(ETOT + 255) / 256, 256, 0, stream>>>(srcp, dstp, row_ptr, fill,
                                                          csr_src, csr_eid);

    // ---- fused layer-1 softmax+aggregate+ELU+split (alpha1 -> d_out) ----
    aggregate1<<<NN, 256, 0, stream>>>(h1b, s_src1, s_dst1, row_ptr, csr_src, csr_eid,
                                       acc1, A2stk, alpha1);

    // ---- layer 2 transforms (fused W2|lin2_W), split-bf16 MFMA ----
    split_Bt<<<(512 * (C1 / 4) + 255) / 256, 256, 0, stream>>>(W2, lin2_W, C1, D2, 512, Bt2);
    gemm_split<64, 4, 1, 64><<<mt * 8, 256, 0, stream>>>(
        A2stk, 2 * C1, 2 * C1, Bt2, 3 * C1, h2b, acc2, NN, D2, D2, 8, lin2_b, b2);

    // ---- fused layer-2 softmax+aggregate -> out ----
    scores_h1<<<(NN + 3) / 4, 256, 0, stream>>>(h2b, att_src2, att_dst2, s_src2, s_dst2);
    aggregate2<<<NN, 64, 0, stream>>>(h2b, s_src2, s_dst2, row_ptr, csr_src, acc2, out);
}